// Round 6
// baseline (482.639 us; speedup 1.0000x reference)
//
#include <hip/hip_runtime.h>

#define FD 128  // feature dim (H = O = 128)

__device__ __forceinline__ float lrelu(float x) { return x > 0.f ? x : 0.2f * x; }

__device__ __forceinline__ void fma4(float4& acc, float s, const float4& w) {
    acc.x = fmaf(s, w.x, acc.x);
    acc.y = fmaf(s, w.y, acc.y);
    acc.z = fmaf(s, w.z, acc.z);
    acc.w = fmaf(s, w.w, acc.w);
}

// bf16 pack/unpack (RNE)
__device__ __forceinline__ unsigned short f2bf(float f) {
    unsigned int u = __float_as_uint(f);
    u = (u + 0x7FFFu + ((u >> 16) & 1u)) >> 16;
    return (unsigned short)u;
}
__device__ __forceinline__ float bf2f(unsigned short h) {
    return __uint_as_float((unsigned int)h << 16);
}

// ---------- CSR build ----------
__global__ void k_zero_int(int* p, int n) {
    int i = blockIdx.x * blockDim.x + threadIdx.x;
    if (i < n) p[i] = 0;
}

__global__ void k_hist(const int* __restrict__ dst, int* cnt, int e) {
    int i = blockIdx.x * blockDim.x + threadIdx.x;
    if (i < e) atomicAdd(&cnt[dst[i]], 1);
}

// inclusive block scan -> rowptr (per-block inclusive), bsum = block totals
__global__ __launch_bounds__(256) void k_scan1(const int* __restrict__ cnt, int* rowptr,
                                               int* bsum, int n) {
    __shared__ int lds[256];
    int i = blockIdx.x * 256 + threadIdx.x;
    int v = (i < n) ? cnt[i] : 0;
    lds[threadIdx.x] = v;
    __syncthreads();
    for (int off = 1; off < 256; off <<= 1) {
        int t = (threadIdx.x >= off) ? lds[threadIdx.x - off] : 0;
        __syncthreads();
        lds[threadIdx.x] += t;
        __syncthreads();
    }
    if (i < n) rowptr[i] = lds[threadIdx.x];
    if (threadIdx.x == 255) bsum[blockIdx.x] = lds[255];
}

// single-block inclusive scan of block sums (nb <= 256)
__global__ __launch_bounds__(256) void k_scan2(int* bsum, int nb) {
    __shared__ int lds[256];
    int v = (threadIdx.x < nb) ? bsum[threadIdx.x] : 0;
    lds[threadIdx.x] = v;
    __syncthreads();
    for (int off = 1; off < 256; off <<= 1) {
        int t = (threadIdx.x >= off) ? lds[threadIdx.x - off] : 0;
        __syncthreads();
        lds[threadIdx.x] += t;
        __syncthreads();
    }
    if (threadIdx.x < nb) bsum[threadIdx.x] = lds[threadIdx.x];
}

// rowptr[i] = exclusive prefix = (inclusive within block) - cnt[i] + prev-block offset
__global__ void k_scan3(int* rowptr, const int* __restrict__ cnt,
                        const int* __restrict__ bsum, int n) {
    int i = blockIdx.x * 256 + threadIdx.x;
    if (i >= n) return;
    int off = (blockIdx.x > 0) ? bsum[blockIdx.x - 1] : 0;
    rowptr[i] = rowptr[i] - cnt[i] + off;
}

__global__ void k_fill(const int* __restrict__ src, const int* __restrict__ dst,
                       const int* __restrict__ rowptr, int* cursor, int* col, int e) {
    int i = blockIdx.x * blockDim.x + threadIdx.x;
    if (i >= e) return;
    int d = dst[i];
    int pos = atomicAdd(&cursor[d], 1);
    col[rowptr[d] + pos] = src[i];
}

__global__ void k_dinv(const int* __restrict__ cnt, float* dinv, int n) {
    int i = blockIdx.x * blockDim.x + threadIdx.x;
    if (i < n) dinv[i] = rsqrtf((float)cnt[i] + 1.0f);  // +1 self-loop
}

// ---------- GEMM: C[n,128] = act(A[n,128] @ W[128,128] (+ b)) ----------
// W staged in LDS (64 KB) once per block; block = 256 threads covers 64 rows;
// thread computes 8 rows x 4 cols. Output fp32 or bf16 (BF16OUT).
// AV epilogue: asrc[row]=g.a_src, adst[row]=g.a_dst from fp32 accumulators
// via intra-32-lane shuffle reduction.
template <bool BIAS_RELU, bool AV, bool BF16OUT>
__global__ __launch_bounds__(256) void k_gemm128(const float* __restrict__ A,
                                                 const float* __restrict__ W,
                                                 const float* __restrict__ b,
                                                 float* Cf, unsigned short* Ch,
                                                 const float* __restrict__ av_s,
                                                 const float* __restrict__ av_d,
                                                 float* asrc, float* adst, int n) {
    __shared__ float Ws[FD * FD];
    #pragma unroll
    for (int i = 0; i < 16; ++i) {
        int idx = (threadIdx.x + i * 256) * 4;
        *(float4*)&Ws[idx] = *(const float4*)&W[idx];
    }
    __syncthreads();

    const int tx = threadIdx.x & 31;   // col group: cols tx*4 .. tx*4+3
    const int ty = threadIdx.x >> 5;   // row subgroup 0..7
    const int c0 = tx * 4;
    const int row0 = blockIdx.x * 64 + ty * 8;

    const float* Ap[8];
    #pragma unroll
    for (int r = 0; r < 8; ++r) Ap[r] = A + (size_t)min(row0 + r, n - 1) * FD;

    float4 acc[8];
    #pragma unroll
    for (int r = 0; r < 8; ++r) acc[r] = make_float4(0.f, 0.f, 0.f, 0.f);

    for (int k = 0; k < FD; k += 4) {
        float4 w0 = *(const float4*)&Ws[(k + 0) * FD + c0];
        float4 w1 = *(const float4*)&Ws[(k + 1) * FD + c0];
        float4 w2 = *(const float4*)&Ws[(k + 2) * FD + c0];
        float4 w3 = *(const float4*)&Ws[(k + 3) * FD + c0];
        #pragma unroll
        for (int r = 0; r < 8; ++r) {
            float4 a = *(const float4*)(Ap[r] + k);
            fma4(acc[r], a.x, w0);
            fma4(acc[r], a.y, w1);
            fma4(acc[r], a.z, w2);
            fma4(acc[r], a.w, w3);
        }
    }

    float4 bias = {0.f, 0.f, 0.f, 0.f};
    if (BIAS_RELU) bias = *(const float4*)(b + c0);
    float4 as4 = {0.f, 0.f, 0.f, 0.f}, ad4 = as4;
    if (AV) {
        as4 = *(const float4*)(av_s + c0);
        ad4 = *(const float4*)(av_d + c0);
    }

    #pragma unroll
    for (int r = 0; r < 8; ++r) {
        int row = row0 + r;
        float4 v = acc[r];
        if (BIAS_RELU) {
            v.x = fmaxf(v.x + bias.x, 0.f);
            v.y = fmaxf(v.y + bias.y, 0.f);
            v.z = fmaxf(v.z + bias.z, 0.f);
            v.w = fmaxf(v.w + bias.w, 0.f);
        }
        if (row < n) {
            if (BF16OUT) {
                ushort4 o;
                o.x = f2bf(v.x); o.y = f2bf(v.y); o.z = f2bf(v.z); o.w = f2bf(v.w);
                *(ushort4*)(Ch + (size_t)row * FD + c0) = o;
            } else {
                *(float4*)(Cf + (size_t)row * FD + c0) = v;
            }
        }
        if (AV) {
            float ps = v.x * as4.x + v.y * as4.y + v.z * as4.z + v.w * as4.w;
            float pd = v.x * ad4.x + v.y * ad4.y + v.z * ad4.z + v.w * ad4.w;
            #pragma unroll
            for (int m = 16; m; m >>= 1) {
                ps += __shfl_xor(ps, m, 32);
                pd += __shfl_xor(pd, m, 32);
            }
            if (tx == 0 && row < n) { asrc[row] = ps; adst[row] = pd; }
        }
    }
}

// ---------- fused gather over bf16 rows ----------
// one wave per node; 2 edges processed per iteration (32 lanes each, 4 cols/lane).
// MODE 0 (GCN): out[d] = relu( sum_{s in N(d)+self} dinv[s]*dinv[d]*m[s] + bias )
// MODE 1 (GAT): out[d] = ( sum w_sd g[s] ) / ( sum w_sd ), w = exp(lrelu(asrc[s]+adst[d]))
template <int MODE>
__global__ __launch_bounds__(256) void k_gather(const unsigned short* __restrict__ m,
                                                const int* __restrict__ col,
                                                const int* __restrict__ rowptr,
                                                const int* __restrict__ cnt,
                                                const float* __restrict__ dinv,
                                                const float* __restrict__ bias,
                                                const float* __restrict__ asrc,
                                                const float* __restrict__ adst,
                                                float* __restrict__ out, int n) {
    const int wave = threadIdx.x >> 6;
    const int lane = threadIdx.x & 63;
    const int half = lane >> 5;
    const int l32 = lane & 31;
    const int d = blockIdx.x * 4 + wave;
    if (d >= n) return;
    const int c0 = l32 * 4;

    const float sd = (MODE == 0) ? dinv[d] : adst[d];  // dd or ad

    float4 acc = {0.f, 0.f, 0.f, 0.f};
    float denom = 0.f;

    // self term (half 0 only)
    if (half == 0) {
        float w = (MODE == 0) ? sd * sd : expf(lrelu(asrc[d] + sd));
        ushort4 u = *(const ushort4*)(m + (size_t)d * FD + c0);
        acc.x = w * bf2f(u.x);
        acc.y = w * bf2f(u.y);
        acc.z = w * bf2f(u.z);
        acc.w = w * bf2f(u.w);
        denom = w;
    }

    const int beg = rowptr[d];
    const int deg = cnt[d];
    for (int j = half; j < deg; j += 2) {
        int s = col[beg + j];
        float w = (MODE == 0) ? sd * dinv[s] : expf(lrelu(asrc[s] + sd));
        ushort4 u = *(const ushort4*)(m + (size_t)s * FD + c0);
        acc.x = fmaf(w, bf2f(u.x), acc.x);
        acc.y = fmaf(w, bf2f(u.y), acc.y);
        acc.z = fmaf(w, bf2f(u.z), acc.z);
        acc.w = fmaf(w, bf2f(u.w), acc.w);
        denom += w;
    }

    // merge the two halves
    acc.x += __shfl_xor(acc.x, 32);
    acc.y += __shfl_xor(acc.y, 32);
    acc.z += __shfl_xor(acc.z, 32);
    acc.w += __shfl_xor(acc.w, 32);
    if (MODE == 1) denom += __shfl_xor(denom, 32);

    if (half == 0) {
        float4 o;
        if (MODE == 0) {
            float4 bb = *(const float4*)(bias + c0);
            o.x = fmaxf(acc.x + bb.x, 0.f);
            o.y = fmaxf(acc.y + bb.y, 0.f);
            o.z = fmaxf(acc.z + bb.z, 0.f);
            o.w = fmaxf(acc.w + bb.w, 0.f);
        } else {
            float inv = 1.0f / denom;
            o.x = acc.x * inv; o.y = acc.y * inv; o.z = acc.z * inv; o.w = acc.w * inv;
        }
        *(float4*)(out + (size_t)d * FD + c0) = o;
    }
}

// ---------- final mean over nodes ----------
__global__ void k_zero_out(float* out) { out[threadIdx.x] = 0.f; }

__global__ void k_reduce_plain(const float* __restrict__ val, float* out, int n) {
    const int sub = threadIdx.x >> 7;  // 0..1
    const int c = threadIdx.x & 127;
    float r = 0.f;
    for (int i = blockIdx.x * 2 + sub; i < n; i += gridDim.x * 2)
        r += val[(size_t)i * FD + c];
    __shared__ float lds[256];
    lds[threadIdx.x] = r;
    __syncthreads();
    if (threadIdx.x < 128) atomicAdd(&out[c], lds[threadIdx.x] + lds[threadIdx.x + 128]);
}

__global__ void k_final(float* out, const float* __restrict__ bg, float invn) {
    int c = threadIdx.x;
    out[c] = out[c] * invn + bg[c];
}

// ---------- launch ----------
extern "C" void kernel_launch(void* const* d_in, const int* in_sizes, int n_in,
                              void* d_out, int out_size, void* d_ws, size_t ws_size,
                              hipStream_t stream) {
    const float* x      = (const float*)d_in[0];
    const int*   ei     = (const int*)d_in[1];
    const float* W_emb  = (const float*)d_in[2];
    const float* b_emb  = (const float*)d_in[3];
    const float* W1     = (const float*)d_in[4];
    const float* b1     = (const float*)d_in[5];
    const float* W2     = (const float*)d_in[6];
    const float* b2     = (const float*)d_in[7];
    const float* Wg     = (const float*)d_in[8];
    const float* a_src  = (const float*)d_in[9];
    const float* a_dst  = (const float*)d_in[10];
    const float* bg     = (const float*)d_in[11];

    const int n = in_sizes[0] / FD;   // 50000
    const int e = in_sizes[1] / 2;    // 800000
    const int* src = ei;
    const int* dst = ei + e;

    float*          bufF = (float*)d_ws;                        // n*128 fp32
    unsigned short* bufM = (unsigned short*)(bufF + (size_t)n * FD);  // n*128 bf16
    float* dinv  = (float*)(bufM + (size_t)n * FD);
    float* asrc  = dinv + n;
    float* adst  = asrc + n;
    int*   cnt    = (int*)(adst + n);
    int*   rowptr = cnt + n;
    int*   cursor = rowptr + n;
    int*   col    = cursor + n;
    int*   bsum   = col + e;

    const dim3 B(256);
    const int gn     = (n + 255) / 256;   // 196 blocks (<= 256, required by scan2)
    const int ge     = (e + 255) / 256;
    const int gnode4 = (n + 3) / 4;
    const int gb64   = (n + 63) / 64;

    // ---- CSR build (counting sort by destination) ----
    k_zero_int<<<gn, B, 0, stream>>>(cnt, n);
    k_zero_int<<<gn, B, 0, stream>>>(cursor, n);
    k_hist<<<ge, B, 0, stream>>>(dst, cnt, e);
    k_scan1<<<gn, B, 0, stream>>>(cnt, rowptr, bsum, n);
    k_scan2<<<1, B, 0, stream>>>(bsum, gn);
    k_scan3<<<gn, B, 0, stream>>>(rowptr, cnt, bsum, n);
    k_fill<<<ge, B, 0, stream>>>(src, dst, rowptr, cursor, col, e);
    k_dinv<<<gn, B, 0, stream>>>(cnt, dinv, n);

    // ---- h0 = relu(x @ W_emb + b_emb) -> bufF (fp32) ----
    k_gemm128<true, false, false><<<gb64, B, 0, stream>>>(x, W_emb, b_emb, bufF, nullptr,
                                                          nullptr, nullptr, nullptr, nullptr, n);

    // ---- GCN layer 1: m1 = h0@W1 (bf16) ; h1 = relu(agg + b1) -> bufF ----
    k_gemm128<false, false, true><<<gb64, B, 0, stream>>>(bufF, W1, nullptr, nullptr, bufM,
                                                          nullptr, nullptr, nullptr, nullptr, n);
    k_gather<0><<<gnode4, B, 0, stream>>>(bufM, col, rowptr, cnt, dinv, b1,
                                          nullptr, nullptr, bufF, n);

    // ---- GCN layer 2: m2 = h1@W2 (bf16) ; h2 = relu(agg + b2) -> bufF ----
    k_gemm128<false, false, true><<<gb64, B, 0, stream>>>(bufF, W2, nullptr, nullptr, bufM,
                                                          nullptr, nullptr, nullptr, nullptr, n);
    k_gather<0><<<gnode4, B, 0, stream>>>(bufM, col, rowptr, cnt, dinv, b2,
                                          nullptr, nullptr, bufF, n);

    // ---- GAT: g = h2@Wg (bf16) + fused a_src/a_dst projections ----
    k_gemm128<false, true, true><<<gb64, B, 0, stream>>>(bufF, Wg, nullptr, nullptr, bufM,
                                                         a_src, a_dst, asrc, adst, n);
    k_gather<1><<<gnode4, B, 0, stream>>>(bufM, col, rowptr, cnt, nullptr, nullptr,
                                          asrc, adst, bufF, n);

    // ---- out[c] = mean_i val[i][c] + bg[c] ----
    k_zero_out<<<1, FD, 0, stream>>>((float*)d_out);
    k_reduce_plain<<<256, B, 0, stream>>>(bufF, (float*)d_out, n);
    k_final<<<1, FD, 0, stream>>>((float*)d_out, bg, 1.0f / n);
}

// Round 7
// 396.764 us; speedup vs baseline: 1.2164x; 1.2164x over previous
//
#include <hip/hip_runtime.h>

#define FD 128  // feature dim (H = O = 128)

__device__ __forceinline__ float lrelu(float x) { return x > 0.f ? x : 0.2f * x; }

__device__ __forceinline__ void fma4(float4& acc, float s, const float4& w) {
    acc.x = fmaf(s, w.x, acc.x);
    acc.y = fmaf(s, w.y, acc.y);
    acc.z = fmaf(s, w.z, acc.z);
    acc.w = fmaf(s, w.w, acc.w);
}

// bf16 pack/unpack (RNE)
__device__ __forceinline__ unsigned short f2bf(float f) {
    unsigned int u = __float_as_uint(f);
    u = (u + 0x7FFFu + ((u >> 16) & 1u)) >> 16;
    return (unsigned short)u;
}
__device__ __forceinline__ float bf2f(unsigned short h) {
    return __uint_as_float((unsigned int)h << 16);
}

// ---------- CSR build ----------
__global__ void k_zero_int(int* p, int n) {
    int i = blockIdx.x * blockDim.x + threadIdx.x;
    if (i < n) p[i] = 0;
}

__global__ void k_hist(const int* __restrict__ dst, int* cnt, int e) {
    int i = blockIdx.x * blockDim.x + threadIdx.x;
    if (i < e) atomicAdd(&cnt[dst[i]], 1);
}

// inclusive block scan -> rowptr (per-block inclusive), bsum = block totals
__global__ __launch_bounds__(256) void k_scan1(const int* __restrict__ cnt, int* rowptr,
                                               int* bsum, int n) {
    __shared__ int lds[256];
    int i = blockIdx.x * 256 + threadIdx.x;
    int v = (i < n) ? cnt[i] : 0;
    lds[threadIdx.x] = v;
    __syncthreads();
    for (int off = 1; off < 256; off <<= 1) {
        int t = (threadIdx.x >= off) ? lds[threadIdx.x - off] : 0;
        __syncthreads();
        lds[threadIdx.x] += t;
        __syncthreads();
    }
    if (i < n) rowptr[i] = lds[threadIdx.x];
    if (threadIdx.x == 255) bsum[blockIdx.x] = lds[255];
}

// single-block inclusive scan of block sums (nb <= 256)
__global__ __launch_bounds__(256) void k_scan2(int* bsum, int nb) {
    __shared__ int lds[256];
    int v = (threadIdx.x < nb) ? bsum[threadIdx.x] : 0;
    lds[threadIdx.x] = v;
    __syncthreads();
    for (int off = 1; off < 256; off <<= 1) {
        int t = (threadIdx.x >= off) ? lds[threadIdx.x - off] : 0;
        __syncthreads();
        lds[threadIdx.x] += t;
        __syncthreads();
    }
    if (threadIdx.x < nb) bsum[threadIdx.x] = lds[threadIdx.x];
}

// rowptr[i] = exclusive prefix = (inclusive within block) - cnt[i] + prev-block offset
__global__ void k_scan3(int* rowptr, const int* __restrict__ cnt,
                        const int* __restrict__ bsum, int n) {
    int i = blockIdx.x * 256 + threadIdx.x;
    if (i >= n) return;
    int off = (blockIdx.x > 0) ? bsum[blockIdx.x - 1] : 0;
    rowptr[i] = rowptr[i] - cnt[i] + off;
}

__global__ void k_fill(const int* __restrict__ src, const int* __restrict__ dst,
                       const int* __restrict__ rowptr, int* cursor, int* col, int e) {
    int i = blockIdx.x * blockDim.x + threadIdx.x;
    if (i >= e) return;
    int d = dst[i];
    int pos = atomicAdd(&cursor[d], 1);
    col[rowptr[d] + pos] = src[i];
}

__global__ void k_dinv(const int* __restrict__ cnt, float* dinv, int n) {
    int i = blockIdx.x * blockDim.x + threadIdx.x;
    if (i < n) dinv[i] = rsqrtf((float)cnt[i] + 1.0f);  // +1 self-loop
}

// ---------- GEMM: C[n,128] = act(A[n,128] @ W[128,128] (+ b)) ----------
// W staged in LDS (64 KB) once per block; block = 512 threads covers 128 rows
// (2 blocks/CU despite 64KB LDS -> 16 waves/CU). Thread: 8 rows x 4 cols.
// Output fp32 or bf16. AV epilogue computes asrc/adst from fp32 accumulators.
template <bool BIAS_RELU, bool AV, bool BF16OUT>
__global__ __launch_bounds__(512) void k_gemm128(const float* __restrict__ A,
                                                 const float* __restrict__ W,
                                                 const float* __restrict__ b,
                                                 float* Cf, unsigned short* Ch,
                                                 const float* __restrict__ av_s,
                                                 const float* __restrict__ av_d,
                                                 float* asrc, float* adst, int n) {
    __shared__ float Ws[FD * FD];
    #pragma unroll
    for (int i = 0; i < 8; ++i) {
        int idx = (threadIdx.x + i * 512) * 4;
        *(float4*)&Ws[idx] = *(const float4*)&W[idx];
    }
    __syncthreads();

    const int tx = threadIdx.x & 31;   // col group: cols tx*4 .. tx*4+3
    const int ty = threadIdx.x >> 5;   // row subgroup 0..15
    const int c0 = tx * 4;
    const int row0 = blockIdx.x * 128 + ty * 8;

    const float* Ap[8];
    #pragma unroll
    for (int r = 0; r < 8; ++r) Ap[r] = A + (size_t)min(row0 + r, n - 1) * FD;

    float4 acc[8];
    #pragma unroll
    for (int r = 0; r < 8; ++r) acc[r] = make_float4(0.f, 0.f, 0.f, 0.f);

    for (int k = 0; k < FD; k += 4) {
        float4 w0 = *(const float4*)&Ws[(k + 0) * FD + c0];
        float4 w1 = *(const float4*)&Ws[(k + 1) * FD + c0];
        float4 w2 = *(const float4*)&Ws[(k + 2) * FD + c0];
        float4 w3 = *(const float4*)&Ws[(k + 3) * FD + c0];
        #pragma unroll
        for (int r = 0; r < 8; ++r) {
            float4 a = *(const float4*)(Ap[r] + k);
            fma4(acc[r], a.x, w0);
            fma4(acc[r], a.y, w1);
            fma4(acc[r], a.z, w2);
            fma4(acc[r], a.w, w3);
        }
    }

    float4 bias = {0.f, 0.f, 0.f, 0.f};
    if (BIAS_RELU) bias = *(const float4*)(b + c0);
    float4 as4 = {0.f, 0.f, 0.f, 0.f}, ad4 = as4;
    if (AV) {
        as4 = *(const float4*)(av_s + c0);
        ad4 = *(const float4*)(av_d + c0);
    }

    #pragma unroll
    for (int r = 0; r < 8; ++r) {
        int row = row0 + r;
        float4 v = acc[r];
        if (BIAS_RELU) {
            v.x = fmaxf(v.x + bias.x, 0.f);
            v.y = fmaxf(v.y + bias.y, 0.f);
            v.z = fmaxf(v.z + bias.z, 0.f);
            v.w = fmaxf(v.w + bias.w, 0.f);
        }
        if (row < n) {
            if (BF16OUT) {
                ushort4 o;
                o.x = f2bf(v.x); o.y = f2bf(v.y); o.z = f2bf(v.z); o.w = f2bf(v.w);
                *(ushort4*)(Ch + (size_t)row * FD + c0) = o;
            } else {
                *(float4*)(Cf + (size_t)row * FD + c0) = v;
            }
        }
        if (AV) {
            float ps = v.x * as4.x + v.y * as4.y + v.z * as4.z + v.w * as4.w;
            float pd = v.x * ad4.x + v.y * ad4.y + v.z * ad4.z + v.w * ad4.w;
            #pragma unroll
            for (int m = 16; m; m >>= 1) {
                ps += __shfl_xor(ps, m, 32);
                pd += __shfl_xor(pd, m, 32);
            }
            if (tx == 0 && row < n) { asrc[row] = ps; adst[row] = pd; }
        }
    }
}

// ---------- fused gather over bf16 rows ----------
// one wave per node; two halves (32 lanes each, 4 cols/lane) take alternate
// edges; each half unrolled x4 -> 8 edges in flight per wave (latency hiding).
// MODE 0 (GCN): out[d] = relu( sum_{s in N(d)+self} dinv[s]*dinv[d]*m[s] + bias )
// MODE 1 (GAT): out[d] = ( sum w_sd g[s] ) / ( sum w_sd ), w = exp(lrelu(asrc[s]+adst[d]))
template <int MODE>
__global__ __launch_bounds__(256) void k_gather(const unsigned short* __restrict__ m,
                                                const int* __restrict__ col,
                                                const int* __restrict__ rowptr,
                                                const int* __restrict__ cnt,
                                                const float* __restrict__ dinv,
                                                const float* __restrict__ bias,
                                                const float* __restrict__ asrc,
                                                const float* __restrict__ adst,
                                                float* __restrict__ out, int n) {
    const int wave = threadIdx.x >> 6;
    const int lane = threadIdx.x & 63;
    const int half = lane >> 5;
    const int l32 = lane & 31;
    const int d = blockIdx.x * 4 + wave;
    if (d >= n) return;
    const int c0 = l32 * 4;

    const float sd = (MODE == 0) ? dinv[d] : adst[d];  // dd or ad

    float4 acc = {0.f, 0.f, 0.f, 0.f};
    float denom = 0.f;

    // self term (half 0 only)
    if (half == 0) {
        float w = (MODE == 0) ? sd * sd : expf(lrelu(asrc[d] + sd));
        ushort4 u = *(const ushort4*)(m + (size_t)d * FD + c0);
        acc.x = w * bf2f(u.x);
        acc.y = w * bf2f(u.y);
        acc.z = w * bf2f(u.z);
        acc.w = w * bf2f(u.w);
        denom = w;
    }

    const int beg = rowptr[d];
    const int deg = cnt[d];
    int j = half;

    // unrolled x4: this half handles edges j, j+2, j+4, j+6
    for (; j + 6 < deg; j += 8) {
        const int s0 = col[beg + j];
        const int s1 = col[beg + j + 2];
        const int s2 = col[beg + j + 4];
        const int s3 = col[beg + j + 6];
        const ushort4 u0 = *(const ushort4*)(m + (size_t)s0 * FD + c0);
        const ushort4 u1 = *(const ushort4*)(m + (size_t)s1 * FD + c0);
        const ushort4 u2 = *(const ushort4*)(m + (size_t)s2 * FD + c0);
        const ushort4 u3 = *(const ushort4*)(m + (size_t)s3 * FD + c0);
        float w0, w1, w2, w3;
        if (MODE == 0) {
            w0 = sd * dinv[s0]; w1 = sd * dinv[s1];
            w2 = sd * dinv[s2]; w3 = sd * dinv[s3];
        } else {
            w0 = expf(lrelu(asrc[s0] + sd)); w1 = expf(lrelu(asrc[s1] + sd));
            w2 = expf(lrelu(asrc[s2] + sd)); w3 = expf(lrelu(asrc[s3] + sd));
        }
        acc.x = fmaf(w0, bf2f(u0.x), acc.x); acc.y = fmaf(w0, bf2f(u0.y), acc.y);
        acc.z = fmaf(w0, bf2f(u0.z), acc.z); acc.w = fmaf(w0, bf2f(u0.w), acc.w);
        acc.x = fmaf(w1, bf2f(u1.x), acc.x); acc.y = fmaf(w1, bf2f(u1.y), acc.y);
        acc.z = fmaf(w1, bf2f(u1.z), acc.z); acc.w = fmaf(w1, bf2f(u1.w), acc.w);
        acc.x = fmaf(w2, bf2f(u2.x), acc.x); acc.y = fmaf(w2, bf2f(u2.y), acc.y);
        acc.z = fmaf(w2, bf2f(u2.z), acc.z); acc.w = fmaf(w2, bf2f(u2.w), acc.w);
        acc.x = fmaf(w3, bf2f(u3.x), acc.x); acc.y = fmaf(w3, bf2f(u3.y), acc.y);
        acc.z = fmaf(w3, bf2f(u3.z), acc.z); acc.w = fmaf(w3, bf2f(u3.w), acc.w);
        if (MODE == 1) denom += w0 + w1 + w2 + w3;
    }
    // tail
    for (; j < deg; j += 2) {
        const int s = col[beg + j];
        const ushort4 u = *(const ushort4*)(m + (size_t)s * FD + c0);
        float w;
        if (MODE == 0) w = sd * dinv[s];
        else           w = expf(lrelu(asrc[s] + sd));
        acc.x = fmaf(w, bf2f(u.x), acc.x); acc.y = fmaf(w, bf2f(u.y), acc.y);
        acc.z = fmaf(w, bf2f(u.z), acc.z); acc.w = fmaf(w, bf2f(u.w), acc.w);
        if (MODE == 1) denom += w;
    }

    // merge the two halves
    acc.x += __shfl_xor(acc.x, 32);
    acc.y += __shfl_xor(acc.y, 32);
    acc.z += __shfl_xor(acc.z, 32);
    acc.w += __shfl_xor(acc.w, 32);
    if (MODE == 1) denom += __shfl_xor(denom, 32);

    if (half == 0) {
        float4 o;
        if (MODE == 0) {
            float4 bb = *(const float4*)(bias + c0);
            o.x = fmaxf(acc.x + bb.x, 0.f);
            o.y = fmaxf(acc.y + bb.y, 0.f);
            o.z = fmaxf(acc.z + bb.z, 0.f);
            o.w = fmaxf(acc.w + bb.w, 0.f);
        } else {
            float inv = 1.0f / denom;
            o.x = acc.x * inv; o.y = acc.y * inv; o.z = acc.z * inv; o.w = acc.w * inv;
        }
        *(float4*)(out + (size_t)d * FD + c0) = o;
    }
}

// ---------- final mean over nodes ----------
__global__ void k_zero_out(float* out) { out[threadIdx.x] = 0.f; }

__global__ void k_reduce_plain(const float* __restrict__ val, float* out, int n) {
    const int sub = threadIdx.x >> 7;  // 0..1
    const int c = threadIdx.x & 127;
    float r = 0.f;
    for (int i = blockIdx.x * 2 + sub; i < n; i += gridDim.x * 2)
        r += val[(size_t)i * FD + c];
    __shared__ float lds[256];
    lds[threadIdx.x] = r;
    __syncthreads();
    if (threadIdx.x < 128) atomicAdd(&out[c], lds[threadIdx.x] + lds[threadIdx.x + 128]);
}

__global__ void k_final(float* out, const float* __restrict__ bg, float invn) {
    int c = threadIdx.x;
    out[c] = out[c] * invn + bg[c];
}

// ---------- launch ----------
extern "C" void kernel_launch(void* const* d_in, const int* in_sizes, int n_in,
                              void* d_out, int out_size, void* d_ws, size_t ws_size,
                              hipStream_t stream) {
    const float* x      = (const float*)d_in[0];
    const int*   ei     = (const int*)d_in[1];
    const float* W_emb  = (const float*)d_in[2];
    const float* b_emb  = (const float*)d_in[3];
    const float* W1     = (const float*)d_in[4];
    const float* b1     = (const float*)d_in[5];
    const float* W2     = (const float*)d_in[6];
    const float* b2     = (const float*)d_in[7];
    const float* Wg     = (const float*)d_in[8];
    const float* a_src  = (const float*)d_in[9];
    const float* a_dst  = (const float*)d_in[10];
    const float* bg     = (const float*)d_in[11];

    const int n = in_sizes[0] / FD;   // 50000
    const int e = in_sizes[1] / 2;    // 800000
    const int* src = ei;
    const int* dst = ei + e;

    float*          bufF = (float*)d_ws;                              // n*128 fp32
    unsigned short* bufM = (unsigned short*)(bufF + (size_t)n * FD);  // n*128 bf16
    float* dinv  = (float*)(bufM + (size_t)n * FD);
    float* asrc  = dinv + n;
    float* adst  = asrc + n;
    int*   cnt    = (int*)(adst + n);
    int*   rowptr = cnt + n;
    int*   cursor = rowptr + n;
    int*   col    = cursor + n;
    int*   bsum   = col + e;

    const dim3 B(256);
    const int gn     = (n + 255) / 256;   // 196 blocks (<= 256, required by scan2)
    const int ge     = (e + 255) / 256;
    const int gnode4 = (n + 3) / 4;
    const int gb128  = (n + 127) / 128;

    // ---- CSR build (counting sort by destination) ----
    k_zero_int<<<gn, B, 0, stream>>>(cnt, n);
    k_zero_int<<<gn, B, 0, stream>>>(cursor, n);
    k_hist<<<ge, B, 0, stream>>>(dst, cnt, e);
    k_scan1<<<gn, B, 0, stream>>>(cnt, rowptr, bsum, n);
    k_scan2<<<1, B, 0, stream>>>(bsum, gn);
    k_scan3<<<gn, B, 0, stream>>>(rowptr, cnt, bsum, n);
    k_fill<<<ge, B, 0, stream>>>(src, dst, rowptr, cursor, col, e);
    k_dinv<<<gn, B, 0, stream>>>(cnt, dinv, n);

    // ---- h0 = relu(x @ W_emb + b_emb) -> bufF (fp32) ----
    k_gemm128<true, false, false><<<gb128, 512, 0, stream>>>(x, W_emb, b_emb, bufF, nullptr,
                                                             nullptr, nullptr, nullptr, nullptr, n);

    // ---- GCN layer 1: m1 = h0@W1 (bf16) ; h1 = relu(agg + b1) -> bufF ----
    k_gemm128<false, false, true><<<gb128, 512, 0, stream>>>(bufF, W1, nullptr, nullptr, bufM,
                                                             nullptr, nullptr, nullptr, nullptr, n);
    k_gather<0><<<gnode4, B, 0, stream>>>(bufM, col, rowptr, cnt, dinv, b1,
                                          nullptr, nullptr, bufF, n);

    // ---- GCN layer 2: m2 = h1@W2 (bf16) ; h2 = relu(agg + b2) -> bufF ----
    k_gemm128<false, false, true><<<gb128, 512, 0, stream>>>(bufF, W2, nullptr, nullptr, bufM,
                                                             nullptr, nullptr, nullptr, nullptr, n);
    k_gather<0><<<gnode4, B, 0, stream>>>(bufM, col, rowptr, cnt, dinv, b2,
                                          nullptr, nullptr, bufF, n);

    // ---- GAT: g = h2@Wg (bf16) + fused a_src/a_dst projections ----
    k_gemm128<false, true, true><<<gb128, 512, 0, stream>>>(bufF, Wg, nullptr, nullptr, bufM,
                                                            a_src, a_dst, asrc, adst, n);
    k_gather<1><<<gnode4, B, 0, stream>>>(bufM, col, rowptr, cnt, nullptr, nullptr,
                                          asrc, adst, bufF, n);

    // ---- out[c] = mean_i val[i][c] + bg[c] ----
    k_zero_out<<<1, FD, 0, stream>>>((float*)d_out);
    k_reduce_plain<<<256, B, 0, stream>>>(bufF, (float*)d_out, n);
    k_final<<<1, FD, 0, stream>>>((float*)d_out, bg, 1.0f / n);
}

// Round 8
// 298.841 us; speedup vs baseline: 1.6150x; 1.3277x over previous
//
#include <hip/hip_runtime.h>

#define FD 128  // feature dim (H = O = 128)

typedef __attribute__((ext_vector_type(8))) short bf16x8;
typedef __attribute__((ext_vector_type(4))) float f32x4;

__device__ __forceinline__ float lrelu(float x) { return x > 0.f ? x : 0.2f * x; }

// bf16 pack/unpack (RNE)
__device__ __forceinline__ unsigned short f2bf(float f) {
    unsigned int u = __float_as_uint(f);
    u = (u + 0x7FFFu + ((u >> 16) & 1u)) >> 16;
    return (unsigned short)u;
}
__device__ __forceinline__ float bf2f(unsigned short h) {
    return __uint_as_float((unsigned int)h << 16);
}

// ---------- CSR build ----------
__global__ void k_zero_int(int* p, int n) {
    int i = blockIdx.x * blockDim.x + threadIdx.x;
    if (i < n) p[i] = 0;
}

// histogram, 4 edges/thread for memory-level parallelism
__global__ __launch_bounds__(256) void k_hist(const int* __restrict__ dst, int* cnt, int e) {
    int i0 = blockIdx.x * 1024 + threadIdx.x;
    int i1 = i0 + 256, i2 = i0 + 512, i3 = i0 + 768;
    int d0 = (i0 < e) ? dst[i0] : 0;
    int d1 = (i1 < e) ? dst[i1] : 0;
    int d2 = (i2 < e) ? dst[i2] : 0;
    int d3 = (i3 < e) ? dst[i3] : 0;
    if (i0 < e) atomicAdd(&cnt[d0], 1);
    if (i1 < e) atomicAdd(&cnt[d1], 1);
    if (i2 < e) atomicAdd(&cnt[d2], 1);
    if (i3 < e) atomicAdd(&cnt[d3], 1);
}

// inclusive block scan -> rowptr (per-block inclusive), bsum = block totals
__global__ __launch_bounds__(256) void k_scan1(const int* __restrict__ cnt, int* rowptr,
                                               int* bsum, int n) {
    __shared__ int lds[256];
    int i = blockIdx.x * 256 + threadIdx.x;
    int v = (i < n) ? cnt[i] : 0;
    lds[threadIdx.x] = v;
    __syncthreads();
    for (int off = 1; off < 256; off <<= 1) {
        int t = (threadIdx.x >= off) ? lds[threadIdx.x - off] : 0;
        __syncthreads();
        lds[threadIdx.x] += t;
        __syncthreads();
    }
    if (i < n) rowptr[i] = lds[threadIdx.x];
    if (threadIdx.x == 255) bsum[blockIdx.x] = lds[255];
}

// single-block inclusive scan of block sums (nb <= 256)
__global__ __launch_bounds__(256) void k_scan2(int* bsum, int nb) {
    __shared__ int lds[256];
    int v = (threadIdx.x < nb) ? bsum[threadIdx.x] : 0;
    lds[threadIdx.x] = v;
    __syncthreads();
    for (int off = 1; off < 256; off <<= 1) {
        int t = (threadIdx.x >= off) ? lds[threadIdx.x - off] : 0;
        __syncthreads();
        lds[threadIdx.x] += t;
        __syncthreads();
    }
    if (threadIdx.x < nb) bsum[threadIdx.x] = lds[threadIdx.x];
}

// rowptr[i] = exclusive prefix; also dinv[i] = rsqrt(deg+1)
__global__ void k_scan3(int* rowptr, const int* __restrict__ cnt,
                        const int* __restrict__ bsum, float* dinv, int n) {
    int i = blockIdx.x * 256 + threadIdx.x;
    if (i >= n) return;
    int off = (blockIdx.x > 0) ? bsum[blockIdx.x - 1] : 0;
    rowptr[i] = rowptr[i] - cnt[i] + off;
    dinv[i] = rsqrtf((float)cnt[i] + 1.0f);
}

// fill: atomicAdd directly on rowptr (returns absolute slot; rowptr becomes
// segment END after this kernel -> gather uses beg = rp[d] - cnt[d]).
// 4 edges/thread for MLP.
__global__ __launch_bounds__(256) void k_fill(const int* __restrict__ src,
                                              const int* __restrict__ dst,
                                              int* rp, int* col, int e) {
    int i0 = blockIdx.x * 1024 + threadIdx.x;
    int i1 = i0 + 256, i2 = i0 + 512, i3 = i0 + 768;
    int d0 = (i0 < e) ? dst[i0] : 0;
    int d1 = (i1 < e) ? dst[i1] : 0;
    int d2 = (i2 < e) ? dst[i2] : 0;
    int d3 = (i3 < e) ? dst[i3] : 0;
    int s0 = (i0 < e) ? src[i0] : 0;
    int s1 = (i1 < e) ? src[i1] : 0;
    int s2 = (i2 < e) ? src[i2] : 0;
    int s3 = (i3 < e) ? src[i3] : 0;
    int p0 = 0, p1 = 0, p2 = 0, p3 = 0;
    if (i0 < e) p0 = atomicAdd(&rp[d0], 1);
    if (i1 < e) p1 = atomicAdd(&rp[d1], 1);
    if (i2 < e) p2 = atomicAdd(&rp[d2], 1);
    if (i3 < e) p3 = atomicAdd(&rp[d3], 1);
    if (i0 < e) col[p0] = s0;
    if (i1 < e) col[p1] = s1;
    if (i2 < e) col[p2] = s2;
    if (i3 < e) col[p3] = s3;
}

// ---------- fp32 -> bf16 convert (for x) ----------
__global__ void k_cvt(const float* __restrict__ x, unsigned short* __restrict__ o, int total4) {
    int i = blockIdx.x * blockDim.x + threadIdx.x;
    if (i >= total4) return;
    float4 v = ((const float4*)x)[i];
    ushort4 u;
    u.x = f2bf(v.x); u.y = f2bf(v.y); u.z = f2bf(v.z); u.w = f2bf(v.w);
    ((ushort4*)o)[i] = u;
}

// ---------- MFMA GEMM: C[n,128] = act(A[n,128] @ W[128,128] (+ b)), bf16 in/out ----------
// W (fp32) converted+transposed into LDS Wt[j][k] (bf16, row pad to 136 for
// balanced ds_read_b128 banking). Block = 512 threads = 8 waves; wave computes
// 16 rows x 128 cols via 8 N-tiles x 4 K-steps of mfma_f32_16x16x32_bf16.
// Fragment mapping (verified, learn_hip m89): A: row=lane&15, k=8*(lane>>4)+e;
// B: col=lane&15, k=8*(lane>>4)+e; D: col=lane&15, row=4*(lane>>4)+reg.
// AV epilogue (Wg): asrc/adst row-dots from fp32 accumulators.
template <bool BIAS_RELU, bool AV>
__global__ __launch_bounds__(512) void k_gemm_mfma(const unsigned short* __restrict__ A,
                                                   const float* __restrict__ W,
                                                   const float* __restrict__ b,
                                                   unsigned short* __restrict__ C,
                                                   const float* __restrict__ av_s,
                                                   const float* __restrict__ av_d,
                                                   float* asrc, float* adst, int n) {
    __shared__ unsigned short Wt[FD][136];
    for (int idx = threadIdx.x; idx < FD * FD; idx += 512) {
        int k = idx >> 7, j = idx & 127;
        Wt[j][k] = f2bf(W[idx]);
    }
    __syncthreads();

    const int wid = threadIdx.x >> 6;   // wave 0..7
    const int lane = threadIdx.x & 63;
    const int lm = lane & 15;
    const int lh = lane >> 4;           // 0..3
    const int row0 = blockIdx.x * 128 + wid * 16;

    // A fragments for the wave's 16 rows, all 4 K-steps
    const int arow = min(row0 + lm, n - 1);
    const unsigned short* Ar = A + (size_t)arow * FD + lh * 8;
    bf16x8 a0 = *(const bf16x8*)(Ar);
    bf16x8 a1 = *(const bf16x8*)(Ar + 32);
    bf16x8 a2 = *(const bf16x8*)(Ar + 64);
    bf16x8 a3 = *(const bf16x8*)(Ar + 96);

    f32x4 acc[8];
    #pragma unroll
    for (int nt = 0; nt < 8; ++nt) acc[nt] = (f32x4){0.f, 0.f, 0.f, 0.f};

    #pragma unroll
    for (int nt = 0; nt < 8; ++nt) {
        const unsigned short* wp = &Wt[nt * 16 + lm][lh * 8];
        bf16x8 b0 = *(const bf16x8*)(wp);
        bf16x8 b1 = *(const bf16x8*)(wp + 32);
        bf16x8 b2 = *(const bf16x8*)(wp + 64);
        bf16x8 b3 = *(const bf16x8*)(wp + 96);
        acc[nt] = __builtin_amdgcn_mfma_f32_16x16x32_bf16(a0, b0, acc[nt], 0, 0, 0);
        acc[nt] = __builtin_amdgcn_mfma_f32_16x16x32_bf16(a1, b1, acc[nt], 0, 0, 0);
        acc[nt] = __builtin_amdgcn_mfma_f32_16x16x32_bf16(a2, b2, acc[nt], 0, 0, 0);
        acc[nt] = __builtin_amdgcn_mfma_f32_16x16x32_bf16(a3, b3, acc[nt], 0, 0, 0);
    }

    #pragma unroll
    for (int nt = 0; nt < 8; ++nt) {
        const int c = nt * 16 + lm;
        float bv = 0.f;
        if (BIAS_RELU) bv = b[c];
        #pragma unroll
        for (int r = 0; r < 4; ++r) {
            const int row = row0 + 4 * lh + r;
            float v = acc[nt][r];
            if (BIAS_RELU) v = fmaxf(v + bv, 0.f);
            if (row < n) C[(size_t)row * FD + c] = f2bf(v);
        }
    }

    if (AV) {
        float asv[8], adv[8];
        #pragma unroll
        for (int nt = 0; nt < 8; ++nt) {
            asv[nt] = av_s[nt * 16 + lm];
            adv[nt] = av_d[nt * 16 + lm];
        }
        #pragma unroll
        for (int r = 0; r < 4; ++r) {
            float ps = 0.f, pd = 0.f;
            #pragma unroll
            for (int nt = 0; nt < 8; ++nt) {
                ps = fmaf(acc[nt][r], asv[nt], ps);
                pd = fmaf(acc[nt][r], adv[nt], pd);
            }
            #pragma unroll
            for (int m = 1; m < 16; m <<= 1) {
                ps += __shfl_xor(ps, m);
                pd += __shfl_xor(pd, m);
            }
            const int row = row0 + 4 * lh + r;
            if (lm == 0 && row < n) { asrc[row] = ps; adst[row] = pd; }
        }
    }
}

// ---------- fused gather over bf16 rows, bf16 out ----------
// one wave per node; two halves (32 lanes, 4 cols/lane) take alternate edges,
// each half unrolled x4 -> 8 edges in flight per wave.
// rp[] holds segment END (post-fill); beg = rp[d] - cnt[d].
// MODE 0 (GCN): out[d] = relu( sum dinv[s]*dinv[d]*m[s] + bias )
// MODE 1 (GAT): out[d] = ( sum w_sd g[s] ) / ( sum w_sd ), w = exp(lrelu(asrc[s]+adst[d]))
template <int MODE>
__global__ __launch_bounds__(256) void k_gather(const unsigned short* __restrict__ m,
                                                const int* __restrict__ col,
                                                const int* __restrict__ rp,
                                                const int* __restrict__ cnt,
                                                const float* __restrict__ dinv,
                                                const float* __restrict__ bias,
                                                const float* __restrict__ asrc,
                                                const float* __restrict__ adst,
                                                unsigned short* __restrict__ out, int n) {
    const int wave = threadIdx.x >> 6;
    const int lane = threadIdx.x & 63;
    const int half = lane >> 5;
    const int l32 = lane & 31;
    const int d = blockIdx.x * 4 + wave;
    if (d >= n) return;
    const int c0 = l32 * 4;

    const float sd = (MODE == 0) ? dinv[d] : adst[d];

    float4 acc = {0.f, 0.f, 0.f, 0.f};
    float denom = 0.f;

    if (half == 0) {  // self term
        float w = (MODE == 0) ? sd * sd : expf(lrelu(asrc[d] + sd));
        ushort4 u = *(const ushort4*)(m + (size_t)d * FD + c0);
        acc.x = w * bf2f(u.x);
        acc.y = w * bf2f(u.y);
        acc.z = w * bf2f(u.z);
        acc.w = w * bf2f(u.w);
        denom = w;
    }

    const int deg = cnt[d];
    const int beg = rp[d] - deg;
    int j = half;

    for (; j + 6 < deg; j += 8) {
        const int s0 = col[beg + j];
        const int s1 = col[beg + j + 2];
        const int s2 = col[beg + j + 4];
        const int s3 = col[beg + j + 6];
        const ushort4 u0 = *(const ushort4*)(m + (size_t)s0 * FD + c0);
        const ushort4 u1 = *(const ushort4*)(m + (size_t)s1 * FD + c0);
        const ushort4 u2 = *(const ushort4*)(m + (size_t)s2 * FD + c0);
        const ushort4 u3 = *(const ushort4*)(m + (size_t)s3 * FD + c0);
        float w0, w1, w2, w3;
        if (MODE == 0) {
            w0 = sd * dinv[s0]; w1 = sd * dinv[s1];
            w2 = sd * dinv[s2]; w3 = sd * dinv[s3];
        } else {
            w0 = expf(lrelu(asrc[s0] + sd)); w1 = expf(lrelu(asrc[s1] + sd));
            w2 = expf(lrelu(asrc[s2] + sd)); w3 = expf(lrelu(asrc[s3] + sd));
        }
        acc.x = fmaf(w0, bf2f(u0.x), acc.x); acc.y = fmaf(w0, bf2f(u0.y), acc.y);
        acc.z = fmaf(w0, bf2f(u0.z), acc.z); acc.w = fmaf(w0, bf2f(u0.w), acc.w);
        acc.x = fmaf(w1, bf2f(u1.x), acc.x); acc.y = fmaf(w1, bf2f(u1.y), acc.y);
        acc.z = fmaf(w1, bf2f(u1.z), acc.z); acc.w = fmaf(w1, bf2f(u1.w), acc.w);
        acc.x = fmaf(w2, bf2f(u2.x), acc.x); acc.y = fmaf(w2, bf2f(u2.y), acc.y);
        acc.z = fmaf(w2, bf2f(u2.z), acc.z); acc.w = fmaf(w2, bf2f(u2.w), acc.w);
        acc.x = fmaf(w3, bf2f(u3.x), acc.x); acc.y = fmaf(w3, bf2f(u3.y), acc.y);
        acc.z = fmaf(w3, bf2f(u3.z), acc.z); acc.w = fmaf(w3, bf2f(u3.w), acc.w);
        if (MODE == 1) denom += w0 + w1 + w2 + w3;
    }
    for (; j < deg; j += 2) {
        const int s = col[beg + j];
        const ushort4 u = *(const ushort4*)(m + (size_t)s * FD + c0);
        float w;
        if (MODE == 0) w = sd * dinv[s];
        else           w = expf(lrelu(asrc[s] + sd));
        acc.x = fmaf(w, bf2f(u.x), acc.x); acc.y = fmaf(w, bf2f(u.y), acc.y);
        acc.z = fmaf(w, bf2f(u.z), acc.z); acc.w = fmaf(w, bf2f(u.w), acc.w);
        if (MODE == 1) denom += w;
    }

    acc.x += __shfl_xor(acc.x, 32);
    acc.y += __shfl_xor(acc.y, 32);
    acc.z += __shfl_xor(acc.z, 32);
    acc.w += __shfl_xor(acc.w, 32);
    if (MODE == 1) denom += __shfl_xor(denom, 32);

    if (half == 0) {
        float4 o;
        if (MODE == 0) {
            float4 bb = *(const float4*)(bias + c0);
            o.x = fmaxf(acc.x + bb.x, 0.f);
            o.y = fmaxf(acc.y + bb.y, 0.f);
            o.z = fmaxf(acc.z + bb.z, 0.f);
            o.w = fmaxf(acc.w + bb.w, 0.f);
        } else {
            float inv = 1.0f / denom;
            o.x = acc.x * inv; o.y = acc.y * inv; o.z = acc.z * inv; o.w = acc.w * inv;
        }
        ushort4 ou;
        ou.x = f2bf(o.x); ou.y = f2bf(o.y); ou.z = f2bf(o.z); ou.w = f2bf(o.w);
        *(ushort4*)(out + (size_t)d * FD + c0) = ou;
    }
}

// ---------- final mean over nodes ----------
__global__ void k_zero_out(float* out) { out[threadIdx.x] = 0.f; }

__global__ void k_reduce_plain(const unsigned short* __restrict__ val, float* out, int n) {
    const int sub = threadIdx.x >> 7;  // 0..1
    const int c = threadIdx.x & 127;
    float r = 0.f;
    for (int i = blockIdx.x * 2 + sub; i < n; i += gridDim.x * 2)
        r += bf2f(val[(size_t)i * FD + c]);
    __shared__ float lds[256];
    lds[threadIdx.x] = r;
    __syncthreads();
    if (threadIdx.x < 128) atomicAdd(&out[c], lds[threadIdx.x] + lds[threadIdx.x + 128]);
}

__global__ void k_final(float* out, const float* __restrict__ bg, float invn) {
    int c = threadIdx.x;
    out[c] = out[c] * invn + bg[c];
}

// ---------- launch ----------
extern "C" void kernel_launch(void* const* d_in, const int* in_sizes, int n_in,
                              void* d_out, int out_size, void* d_ws, size_t ws_size,
                              hipStream_t stream) {
    const float* x      = (const float*)d_in[0];
    const int*   ei     = (const int*)d_in[1];
    const float* W_emb  = (const float*)d_in[2];
    const float* b_emb  = (const float*)d_in[3];
    const float* W1     = (const float*)d_in[4];
    const float* b1     = (const float*)d_in[5];
    const float* W2     = (const float*)d_in[6];
    const float* b2     = (const float*)d_in[7];
    const float* Wg     = (const float*)d_in[8];
    const float* a_src  = (const float*)d_in[9];
    const float* a_dst  = (const float*)d_in[10];
    const float* bg     = (const float*)d_in[11];

    const int n = in_sizes[0] / FD;   // 50000
    const int e = in_sizes[1] / 2;    // 800000
    const int* src = ei;
    const int* dst = ei + e;

    unsigned short* bufA = (unsigned short*)d_ws;           // n*128 bf16
    unsigned short* bufB = bufA + (size_t)n * FD;           // n*128 bf16
    float* dinv  = (float*)(bufB + (size_t)n * FD);
    float* asrc  = dinv + n;
    float* adst  = asrc + n;
    int*   cnt    = (int*)(adst + n);
    int*   rp     = cnt + n;
    int*   col    = rp + n;
    int*   bsum   = col + e;

    const dim3 B(256);
    const int gn     = (n + 255) / 256;    // 196 (<=256 for scan2)
    const int ge4    = (e + 1023) / 1024;
    const int gnode4 = (n + 3) / 4;
    const int gb128  = (n + 127) / 128;
    const int gcvt   = (n * FD / 4 + 255) / 256;

    // ---- CSR build ----
    k_zero_int<<<gn, B, 0, stream>>>(cnt, n);
    k_hist<<<ge4, B, 0, stream>>>(dst, cnt, e);
    k_scan1<<<gn, B, 0, stream>>>(cnt, rp, bsum, n);
    k_scan2<<<1, B, 0, stream>>>(bsum, gn);
    k_scan3<<<gn, B, 0, stream>>>(rp, cnt, bsum, dinv, n);
    k_fill<<<ge4, B, 0, stream>>>(src, dst, rp, col, e);   // rp -> segment ends

    // ---- x -> bf16 ----
    k_cvt<<<gcvt, B, 0, stream>>>(x, bufA, n * FD / 4);

    // ---- h0 = relu(x @ W_emb + b_emb) -> bufB ----
    k_gemm_mfma<true, false><<<gb128, 512, 0, stream>>>(bufA, W_emb, b_emb, bufB,
                                                        nullptr, nullptr, nullptr, nullptr, n);
    // ---- GCN layer 1 ----
    k_gemm_mfma<false, false><<<gb128, 512, 0, stream>>>(bufB, W1, nullptr, bufA,
                                                         nullptr, nullptr, nullptr, nullptr, n);
    k_gather<0><<<gnode4, B, 0, stream>>>(bufA, col, rp, cnt, dinv, b1,
                                          nullptr, nullptr, bufB, n);
    // ---- GCN layer 2 ----
    k_gemm_mfma<false, false><<<gb128, 512, 0, stream>>>(bufB, W2, nullptr, bufA,
                                                         nullptr, nullptr, nullptr, nullptr, n);
    k_gather<0><<<gnode4, B, 0, stream>>>(bufA, col, rp, cnt, dinv, b2,
                                          nullptr, nullptr, bufB, n);
    // ---- GAT ----
    k_gemm_mfma<false, true><<<gb128, 512, 0, stream>>>(bufB, Wg, nullptr, bufA,
                                                        a_src, a_dst, asrc, adst, n);
    k_gather<1><<<gnode4, B, 0, stream>>>(bufA, col, rp, cnt, nullptr, nullptr,
                                          asrc, adst, bufB, n);

    // ---- out[c] = mean_i val[i][c] + bg[c] ----
    k_zero_out<<<1, FD, 0, stream>>>((float*)d_out);
    k_reduce_plain<<<256, B, 0, stream>>>(bufB, (float*)d_out, n);
    k_final<<<1, FD, 0, stream>>>((float*)d_out, bg, 1.0f / n);
}

// Round 9
// 237.113 us; speedup vs baseline: 2.0355x; 1.2603x over previous
//
#include <hip/hip_runtime.h>

#define FD 128  // feature dim (H = O = 128)

typedef __attribute__((ext_vector_type(8))) short bf16x8;
typedef __attribute__((ext_vector_type(4))) float f32x4;

__device__ __forceinline__ float lrelu(float x) { return x > 0.f ? x : 0.2f * x; }

// bf16 pack/unpack (RNE)
__device__ __forceinline__ unsigned short f2bf(float f) {
    unsigned int u = __float_as_uint(f);
    u = (u + 0x7FFFu + ((u >> 16) & 1u)) >> 16;
    return (unsigned short)u;
}
__device__ __forceinline__ float bf2f(unsigned short h) {
    return __uint_as_float((unsigned int)h << 16);
}

// ================= CSR build: MSD bucket sort, LDS atomics only =================
// Bucket = dst>>8 (256 buckets). NB blocks, chunk = ceil(e/NB) edges each.
#define NB 256

// pass 1a: per-block 256-bin histogram -> ghist[bin*NB + blk] (bin-major)
__global__ __launch_bounds__(256) void k_bhist(const int* __restrict__ dst, int* ghist, int e, int chunk) {
    __shared__ int h[256];
    h[threadIdx.x] = 0;
    __syncthreads();
    const int i0 = blockIdx.x * chunk;
    const int i1 = min(i0 + chunk, e);
    for (int i = i0 + threadIdx.x; i < i1; i += 256)
        atomicAdd(&h[dst[i] >> 8], 1);
    __syncthreads();
    ghist[threadIdx.x * NB + blockIdx.x] = h[threadIdx.x];
}

// generic scan kernels (exclusive scan of ghist -> S)
__global__ __launch_bounds__(256) void k_scan1(const int* __restrict__ v, int* S, int* bsum, int n) {
    __shared__ int lds[256];
    int i = blockIdx.x * 256 + threadIdx.x;
    int x = (i < n) ? v[i] : 0;
    lds[threadIdx.x] = x;
    __syncthreads();
    for (int off = 1; off < 256; off <<= 1) {
        int t = (threadIdx.x >= off) ? lds[threadIdx.x - off] : 0;
        __syncthreads();
        lds[threadIdx.x] += t;
        __syncthreads();
    }
    if (i < n) S[i] = lds[threadIdx.x];
    if (threadIdx.x == 255) bsum[blockIdx.x] = lds[255];
}

__global__ __launch_bounds__(256) void k_scan2(int* bsum, int nb) {
    __shared__ int lds[256];
    int v = (threadIdx.x < nb) ? bsum[threadIdx.x] : 0;
    lds[threadIdx.x] = v;
    __syncthreads();
    for (int off = 1; off < 256; off <<= 1) {
        int t = (threadIdx.x >= off) ? lds[threadIdx.x - off] : 0;
        __syncthreads();
        lds[threadIdx.x] += t;
        __syncthreads();
    }
    if (threadIdx.x < nb) bsum[threadIdx.x] = lds[threadIdx.x];
}

// S[i] = exclusive = (inclusive within block) - v[i] + prev-block offset
__global__ void k_scan3(int* S, const int* __restrict__ v, const int* __restrict__ bsum, int n) {
    int i = blockIdx.x * 256 + threadIdx.x;
    if (i >= n) return;
    int off = (blockIdx.x > 0) ? bsum[blockIdx.x - 1] : 0;
    S[i] = S[i] - v[i] + off;
}

// pass 1b: scatter (dst,src) into bucket-contiguous dstb/srcb via LDS cursors
__global__ __launch_bounds__(256) void k_bscatter(const int* __restrict__ dst,
                                                  const int* __restrict__ src,
                                                  const int* __restrict__ S,
                                                  int* dstb, int* srcb, int e, int chunk) {
    __shared__ int cur[256];
    cur[threadIdx.x] = S[threadIdx.x * NB + blockIdx.x];
    __syncthreads();
    const int i0 = blockIdx.x * chunk;
    const int i1 = min(i0 + chunk, e);
    for (int i = i0 + threadIdx.x; i < i1; i += 256) {
        int d = dst[i];
        int s = src[i];
        int pos = atomicAdd(&cur[d >> 8], 1);
        dstb[pos] = d;
        srcb[pos] = s;
    }
}

// pass 2: one block per bucket b (dst in [256b, 256b+256)).
// Computes cnt, rp (segment END), dinv for those nodes and final col scatter.
__global__ __launch_bounds__(256) void k_bfinal(const int* __restrict__ dstb,
                                                const int* __restrict__ srcb,
                                                const int* __restrict__ S,
                                                int* cnt, int* rp, float* dinv,
                                                int* col, int e, int n) {
    __shared__ int cl[256];   // per-low-byte count
    __shared__ int sc[256];   // scan workspace / cursors
    const int b = blockIdx.x;
    const int base = S[b * NB];                         // bucket start
    const int end = (b < 255) ? S[(b + 1) * NB] : e;    // bucket end
    cl[threadIdx.x] = 0;
    __syncthreads();
    for (int j = base + threadIdx.x; j < end; j += 256)
        atomicAdd(&cl[dstb[j] & 255], 1);
    __syncthreads();
    // inclusive scan of counts
    sc[threadIdx.x] = cl[threadIdx.x];
    __syncthreads();
    for (int off = 1; off < 256; off <<= 1) {
        int t = (threadIdx.x >= off) ? sc[threadIdx.x - off] : 0;
        __syncthreads();
        sc[threadIdx.x] += t;
        __syncthreads();
    }
    const int c = cl[threadIdx.x];
    const int incl = sc[threadIdx.x];
    const int d = b * 256 + threadIdx.x;
    if (d < n) {
        cnt[d] = c;
        rp[d] = base + incl;              // segment end
        dinv[d] = rsqrtf((float)c + 1.0f);
    }
    __syncthreads();
    sc[threadIdx.x] = base + incl - c;    // cursor = segment begin
    __syncthreads();
    for (int j = base + threadIdx.x; j < end; j += 256) {
        int low = dstb[j] & 255;
        int s = srcb[j];
        int pos = atomicAdd(&sc[low], 1);
        col[pos] = s;
    }
}

// ---------- MFMA GEMM: C[n,128] = act(A[n,128] @ W[128,128] (+ b)), bf16 out ----------
// A is bf16 (AFP32=false) or fp32 (AFP32=true, converted in-register).
// W (fp32) converted+transposed into LDS Wt[j][k] (bf16, pad 136).
// Block = 512 threads = 8 waves; wave computes 16 rows x 128 cols via
// 8 N-tiles x 4 K-steps of mfma_f32_16x16x32_bf16.
// AV epilogue (Wg): asrc/adst row-dots from fp32 accumulators.
template <bool BIAS_RELU, bool AV, bool AFP32>
__global__ __launch_bounds__(512) void k_gemm_mfma(const void* __restrict__ Av,
                                                   const float* __restrict__ W,
                                                   const float* __restrict__ b,
                                                   unsigned short* __restrict__ C,
                                                   const float* __restrict__ av_s,
                                                   const float* __restrict__ av_d,
                                                   float* asrc, float* adst, int n) {
    __shared__ unsigned short Wt[FD][136];
    for (int idx = threadIdx.x; idx < FD * FD; idx += 512) {
        int k = idx >> 7, j = idx & 127;
        Wt[j][k] = f2bf(W[idx]);
    }
    __syncthreads();

    const int wid = threadIdx.x >> 6;   // wave 0..7
    const int lane = threadIdx.x & 63;
    const int lm = lane & 15;
    const int lh = lane >> 4;           // 0..3
    const int row0 = blockIdx.x * 128 + wid * 16;

    const int arow = min(row0 + lm, n - 1);
    bf16x8 a0, a1, a2, a3;
    if (AFP32) {
        const float* Ar = (const float*)Av + (size_t)arow * FD + lh * 8;
        #pragma unroll
        for (int kk = 0; kk < 4; ++kk) {
            float4 lo = *(const float4*)(Ar + kk * 32);
            float4 hi = *(const float4*)(Ar + kk * 32 + 4);
            bf16x8 a;
            a[0] = (short)f2bf(lo.x); a[1] = (short)f2bf(lo.y);
            a[2] = (short)f2bf(lo.z); a[3] = (short)f2bf(lo.w);
            a[4] = (short)f2bf(hi.x); a[5] = (short)f2bf(hi.y);
            a[6] = (short)f2bf(hi.z); a[7] = (short)f2bf(hi.w);
            if (kk == 0) a0 = a; else if (kk == 1) a1 = a; else if (kk == 2) a2 = a; else a3 = a;
        }
    } else {
        const unsigned short* Ar = (const unsigned short*)Av + (size_t)arow * FD + lh * 8;
        a0 = *(const bf16x8*)(Ar);
        a1 = *(const bf16x8*)(Ar + 32);
        a2 = *(const bf16x8*)(Ar + 64);
        a3 = *(const bf16x8*)(Ar + 96);
    }

    f32x4 acc[8];
    #pragma unroll
    for (int nt = 0; nt < 8; ++nt) acc[nt] = (f32x4){0.f, 0.f, 0.f, 0.f};

    #pragma unroll
    for (int nt = 0; nt < 8; ++nt) {
        const unsigned short* wp = &Wt[nt * 16 + lm][lh * 8];
        bf16x8 b0 = *(const bf16x8*)(wp);
        bf16x8 b1 = *(const bf16x8*)(wp + 32);
        bf16x8 b2 = *(const bf16x8*)(wp + 64);
        bf16x8 b3 = *(const bf16x8*)(wp + 96);
        acc[nt] = __builtin_amdgcn_mfma_f32_16x16x32_bf16(a0, b0, acc[nt], 0, 0, 0);
        acc[nt] = __builtin_amdgcn_mfma_f32_16x16x32_bf16(a1, b1, acc[nt], 0, 0, 0);
        acc[nt] = __builtin_amdgcn_mfma_f32_16x16x32_bf16(a2, b2, acc[nt], 0, 0, 0);
        acc[nt] = __builtin_amdgcn_mfma_f32_16x16x32_bf16(a3, b3, acc[nt], 0, 0, 0);
    }

    #pragma unroll
    for (int nt = 0; nt < 8; ++nt) {
        const int c = nt * 16 + lm;
        float bv = 0.f;
        if (BIAS_RELU) bv = b[c];
        #pragma unroll
        for (int r = 0; r < 4; ++r) {
            const int row = row0 + 4 * lh + r;
            float v = acc[nt][r];
            if (BIAS_RELU) v = fmaxf(v + bv, 0.f);
            if (row < n) C[(size_t)row * FD + c] = f2bf(v);
        }
    }

    if (AV) {
        float asv[8], adv[8];
        #pragma unroll
        for (int nt = 0; nt < 8; ++nt) {
            asv[nt] = av_s[nt * 16 + lm];
            adv[nt] = av_d[nt * 16 + lm];
        }
        #pragma unroll
        for (int r = 0; r < 4; ++r) {
            float ps = 0.f, pd = 0.f;
            #pragma unroll
            for (int nt = 0; nt < 8; ++nt) {
                ps = fmaf(acc[nt][r], asv[nt], ps);
                pd = fmaf(acc[nt][r], adv[nt], pd);
            }
            #pragma unroll
            for (int m = 1; m < 16; m <<= 1) {
                ps += __shfl_xor(ps, m);
                pd += __shfl_xor(pd, m);
            }
            const int row = row0 + 4 * lh + r;
            if (lm == 0 && row < n) { asrc[row] = ps; adst[row] = pd; }
        }
    }
}

// ---------- fused gather over bf16 rows, bf16 out ----------
// one wave per node; two halves (32 lanes, 4 cols/lane) take alternate edges,
// each half unrolled x4 -> 8 edges in flight per wave.
// rp[] holds segment END; beg = rp[d] - cnt[d].
// MODE 0 (GCN): out[d] = relu( sum dinv[s]*dinv[d]*m[s] + bias )
// MODE 1 (GAT): out[d] = ( sum w_sd g[s] ) / ( sum w_sd ), w = exp(lrelu(asrc[s]+adst[d]))
template <int MODE>
__global__ __launch_bounds__(256) void k_gather(const unsigned short* __restrict__ m,
                                                const int* __restrict__ col,
                                                const int* __restrict__ rp,
                                                const int* __restrict__ cnt,
                                                const float* __restrict__ dinv,
                                                const float* __restrict__ bias,
                                                const float* __restrict__ asrc,
                                                const float* __restrict__ adst,
                                                unsigned short* __restrict__ out, int n) {
    const int wave = threadIdx.x >> 6;
    const int lane = threadIdx.x & 63;
    const int half = lane >> 5;
    const int l32 = lane & 31;
    const int d = blockIdx.x * 4 + wave;
    if (d >= n) return;
    const int c0 = l32 * 4;

    const float sd = (MODE == 0) ? dinv[d] : adst[d];

    float4 acc = {0.f, 0.f, 0.f, 0.f};
    float denom = 0.f;

    if (half == 0) {  // self term
        float w = (MODE == 0) ? sd * sd : expf(lrelu(asrc[d] + sd));
        ushort4 u = *(const ushort4*)(m + (size_t)d * FD + c0);
        acc.x = w * bf2f(u.x);
        acc.y = w * bf2f(u.y);
        acc.z = w * bf2f(u.z);
        acc.w = w * bf2f(u.w);
        denom = w;
    }

    const int deg = cnt[d];
    const int beg = rp[d] - deg;
    int j = half;

    for (; j + 6 < deg; j += 8) {
        const int s0 = col[beg + j];
        const int s1 = col[beg + j + 2];
        const int s2 = col[beg + j + 4];
        const int s3 = col[beg + j + 6];
        const ushort4 u0 = *(const ushort4*)(m + (size_t)s0 * FD + c0);
        const ushort4 u1 = *(const ushort4*)(m + (size_t)s1 * FD + c0);
        const ushort4 u2 = *(const ushort4*)(m + (size_t)s2 * FD + c0);
        const ushort4 u3 = *(const ushort4*)(m + (size_t)s3 * FD + c0);
        float w0, w1, w2, w3;
        if (MODE == 0) {
            w0 = sd * dinv[s0]; w1 = sd * dinv[s1];
            w2 = sd * dinv[s2]; w3 = sd * dinv[s3];
        } else {
            w0 = expf(lrelu(asrc[s0] + sd)); w1 = expf(lrelu(asrc[s1] + sd));
            w2 = expf(lrelu(asrc[s2] + sd)); w3 = expf(lrelu(asrc[s3] + sd));
        }
        acc.x = fmaf(w0, bf2f(u0.x), acc.x); acc.y = fmaf(w0, bf2f(u0.y), acc.y);
        acc.z = fmaf(w0, bf2f(u0.z), acc.z); acc.w = fmaf(w0, bf2f(u0.w), acc.w);
        acc.x = fmaf(w1, bf2f(u1.x), acc.x); acc.y = fmaf(w1, bf2f(u1.y), acc.y);
        acc.z = fmaf(w1, bf2f(u1.z), acc.z); acc.w = fmaf(w1, bf2f(u1.w), acc.w);
        acc.x = fmaf(w2, bf2f(u2.x), acc.x); acc.y = fmaf(w2, bf2f(u2.y), acc.y);
        acc.z = fmaf(w2, bf2f(u2.z), acc.z); acc.w = fmaf(w2, bf2f(u2.w), acc.w);
        acc.x = fmaf(w3, bf2f(u3.x), acc.x); acc.y = fmaf(w3, bf2f(u3.y), acc.y);
        acc.z = fmaf(w3, bf2f(u3.z), acc.z); acc.w = fmaf(w3, bf2f(u3.w), acc.w);
        if (MODE == 1) denom += w0 + w1 + w2 + w3;
    }
    for (; j < deg; j += 2) {
        const int s = col[beg + j];
        const ushort4 u = *(const ushort4*)(m + (size_t)s * FD + c0);
        float w;
        if (MODE == 0) w = sd * dinv[s];
        else           w = expf(lrelu(asrc[s] + sd));
        acc.x = fmaf(w, bf2f(u.x), acc.x); acc.y = fmaf(w, bf2f(u.y), acc.y);
        acc.z = fmaf(w, bf2f(u.z), acc.z); acc.w = fmaf(w, bf2f(u.w), acc.w);
        if (MODE == 1) denom += w;
    }

    acc.x += __shfl_xor(acc.x, 32);
    acc.y += __shfl_xor(acc.y, 32);
    acc.z += __shfl_xor(acc.z, 32);
    acc.w += __shfl_xor(acc.w, 32);
    if (MODE == 1) denom += __shfl_xor(denom, 32);

    if (half == 0) {
        float4 o;
        if (MODE == 0) {
            float4 bb = *(const float4*)(bias + c0);
            o.x = fmaxf(acc.x + bb.x, 0.f);
            o.y = fmaxf(acc.y + bb.y, 0.f);
            o.z = fmaxf(acc.z + bb.z, 0.f);
            o.w = fmaxf(acc.w + bb.w, 0.f);
        } else {
            float inv = 1.0f / denom;
            o.x = acc.x * inv; o.y = acc.y * inv; o.z = acc.z * inv; o.w = acc.w * inv;
        }
        ushort4 ou;
        ou.x = f2bf(o.x); ou.y = f2bf(o.y); ou.z = f2bf(o.z); ou.w = f2bf(o.w);
        *(ushort4*)(out + (size_t)d * FD + c0) = ou;
    }
}

// ---------- final mean over nodes ----------
__global__ void k_zero_out(float* out) { out[threadIdx.x] = 0.f; }

__global__ void k_reduce_plain(const unsigned short* __restrict__ val, float* out, int n) {
    const int sub = threadIdx.x >> 7;  // 0..1
    const int c = threadIdx.x & 127;
    float r = 0.f;
    for (int i = blockIdx.x * 2 + sub; i < n; i += gridDim.x * 2)
        r += bf2f(val[(size_t)i * FD + c]);
    __shared__ float lds[256];
    lds[threadIdx.x] = r;
    __syncthreads();
    if (threadIdx.x < 128) atomicAdd(&out[c], lds[threadIdx.x] + lds[threadIdx.x + 128]);
}

__global__ void k_final(float* out, const float* __restrict__ bg, float invn) {
    int c = threadIdx.x;
    out[c] = out[c] * invn + bg[c];
}

// ---------- launch ----------
extern "C" void kernel_launch(void* const* d_in, const int* in_sizes, int n_in,
                              void* d_out, int out_size, void* d_ws, size_t ws_size,
                              hipStream_t stream) {
    const float* x      = (const float*)d_in[0];
    const int*   ei     = (const int*)d_in[1];
    const float* W_emb  = (const float*)d_in[2];
    const float* b_emb  = (const float*)d_in[3];
    const float* W1     = (const float*)d_in[4];
    const float* b1     = (const float*)d_in[5];
    const float* W2     = (const float*)d_in[6];
    const float* b2     = (const float*)d_in[7];
    const float* Wg     = (const float*)d_in[8];
    const float* a_src  = (const float*)d_in[9];
    const float* a_dst  = (const float*)d_in[10];
    const float* bg     = (const float*)d_in[11];

    const int n = in_sizes[0] / FD;   // 50000
    const int e = in_sizes[1] / 2;    // 800000
    const int* src = ei;
    const int* dst = ei + e;

    unsigned short* bufA = (unsigned short*)d_ws;           // n*128 bf16
    unsigned short* bufB = bufA + (size_t)n * FD;           // n*128 bf16
    float* dinv  = (float*)(bufB + (size_t)n * FD);
    float* asrc  = dinv + n;
    float* adst  = asrc + n;
    int*   cnt   = (int*)(adst + n);
    int*   rp    = cnt + n;
    int*   col   = rp + n;
    int*   dstb  = col + e;
    int*   srcb  = dstb + e;
    int*   ghist = srcb + e;          // 65536
    int*   Sg    = ghist + NB * 256;  // 65536
    int*   bsum  = Sg + NB * 256;     // 256

    const dim3 B(256);
    const int chunk  = (e + NB - 1) / NB;   // 3125
    const int gnode4 = (n + 3) / 4;
    const int gb128  = (n + 127) / 128;

    // ---- CSR build: MSD bucket sort (LDS atomics only) ----
    k_bhist<<<NB, B, 0, stream>>>(dst, ghist, e, chunk);
    k_scan1<<<256, B, 0, stream>>>(ghist, Sg, bsum, NB * 256);
    k_scan2<<<1, B, 0, stream>>>(bsum, 256);
    k_scan3<<<256, B, 0, stream>>>(Sg, ghist, bsum, NB * 256);
    k_bscatter<<<NB, B, 0, stream>>>(dst, src, Sg, dstb, srcb, e, chunk);
    k_bfinal<<<256, B, 0, stream>>>(dstb, srcb, Sg, cnt, rp, dinv, col, e, n);

    // ---- h0 = relu(x @ W_emb + b_emb) -> bufB (x read as fp32, cvt in-reg) ----
    k_gemm_mfma<true, false, true><<<gb128, 512, 0, stream>>>(x, W_emb, b_emb, bufB,
                                                              nullptr, nullptr, nullptr, nullptr, n);
    // ---- GCN layer 1 ----
    k_gemm_mfma<false, false, false><<<gb128, 512, 0, stream>>>(bufB, W1, nullptr, bufA,
                                                                nullptr, nullptr, nullptr, nullptr, n);
    k_gather<0><<<gnode4, B, 0, stream>>>(bufA, col, rp, cnt, dinv, b1,
                                          nullptr, nullptr, bufB, n);
    // ---- GCN layer 2 ----
    k_gemm_mfma<false, false, false><<<gb128, 512, 0, stream>>>(bufB, W2, nullptr, bufA,
                                                                nullptr, nullptr, nullptr, nullptr, n);
    k_gather<0><<<gnode4, B, 0, stream>>>(bufA, col, rp, cnt, dinv, b2,
                                          nullptr, nullptr, bufB, n);
    // ---- GAT ----
    k_gemm_mfma<false, true, false><<<gb128, 512, 0, stream>>>(bufB, Wg, nullptr, bufA,
                                                               a_src, a_dst, asrc, adst, n);
    k_gather<1><<<gnode4, B, 0, stream>>>(bufA, col, rp, cnt, nullptr, nullptr,
                                          asrc, adst, bufB, n);

    // ---- out[c] = mean_i val[i][c] + bg[c] ----
    k_zero_out<<<1, FD, 0, stream>>>((float*)d_out);
    k_reduce_plain<<<256, B, 0, stream>>>(bufB, (float*)d_out, n);
    k_final<<<1, FD, 0, stream>>>((float*)d_out, bg, 1.0f / n);
}

// Round 10
// 229.625 us; speedup vs baseline: 2.1019x; 1.0326x over previous
//
#include <hip/hip_runtime.h>

#define FD 128  // feature dim (H = O = 128)

typedef __attribute__((ext_vector_type(8))) short bf16x8;
typedef __attribute__((ext_vector_type(8))) unsigned short u16x8;
typedef __attribute__((ext_vector_type(4))) float f32x4;

__device__ __forceinline__ float lrelu(float x) { return x > 0.f ? x : 0.2f * x; }

// bf16 pack/unpack (RNE)
__device__ __forceinline__ unsigned short f2bf(float f) {
    unsigned int u = __float_as_uint(f);
    u = (u + 0x7FFFu + ((u >> 16) & 1u)) >> 16;
    return (unsigned short)u;
}
__device__ __forceinline__ float bf2f(unsigned short h) {
    return __uint_as_float((unsigned int)h << 16);
}

// ================= CSR build: MSD bucket sort, LDS atomics only =================
// Bucket = dst>>8 (256 buckets). Payload packed (d<<16)|s (both < 65536).
#define NB 256

__global__ __launch_bounds__(256) void k_bhist(const int* __restrict__ dst, int* ghist, int e, int chunk) {
    __shared__ int h[256];
    h[threadIdx.x] = 0;
    __syncthreads();
    const int i0 = blockIdx.x * chunk;
    const int i1 = min(i0 + chunk, e);
    for (int i = i0 + threadIdx.x; i < i1; i += 256)
        atomicAdd(&h[dst[i] >> 8], 1);
    __syncthreads();
    ghist[threadIdx.x * NB + blockIdx.x] = h[threadIdx.x];
}

__global__ __launch_bounds__(256) void k_scan1(const int* __restrict__ v, int* S, int* bsum, int n) {
    __shared__ int lds[256];
    int i = blockIdx.x * 256 + threadIdx.x;
    int x = (i < n) ? v[i] : 0;
    lds[threadIdx.x] = x;
    __syncthreads();
    for (int off = 1; off < 256; off <<= 1) {
        int t = (threadIdx.x >= off) ? lds[threadIdx.x - off] : 0;
        __syncthreads();
        lds[threadIdx.x] += t;
        __syncthreads();
    }
    if (i < n) S[i] = lds[threadIdx.x];
    if (threadIdx.x == 255) bsum[blockIdx.x] = lds[255];
}

__global__ __launch_bounds__(256) void k_scan2(int* bsum, int nb) {
    __shared__ int lds[256];
    int v = (threadIdx.x < nb) ? bsum[threadIdx.x] : 0;
    lds[threadIdx.x] = v;
    __syncthreads();
    for (int off = 1; off < 256; off <<= 1) {
        int t = (threadIdx.x >= off) ? lds[threadIdx.x - off] : 0;
        __syncthreads();
        lds[threadIdx.x] += t;
        __syncthreads();
    }
    if (threadIdx.x < nb) bsum[threadIdx.x] = lds[threadIdx.x];
}

__global__ void k_scan3(int* S, const int* __restrict__ v, const int* __restrict__ bsum, int n) {
    int i = blockIdx.x * 256 + threadIdx.x;
    if (i >= n) return;
    int off = (blockIdx.x > 0) ? bsum[blockIdx.x - 1] : 0;
    S[i] = S[i] - v[i] + off;
}

__global__ __launch_bounds__(256) void k_bscatter(const int* __restrict__ dst,
                                                  const int* __restrict__ src,
                                                  const int* __restrict__ S,
                                                  int* pk, int e, int chunk) {
    __shared__ int cur[256];
    cur[threadIdx.x] = S[threadIdx.x * NB + blockIdx.x];
    __syncthreads();
    const int i0 = blockIdx.x * chunk;
    const int i1 = min(i0 + chunk, e);
    for (int i = i0 + threadIdx.x; i < i1; i += 256) {
        int d = dst[i];
        int s = src[i];
        int pos = atomicAdd(&cur[d >> 8], 1);
        pk[pos] = (d << 16) | s;
    }
}

// one block per bucket b (dst in [256b, 256b+256)): cnt, rp (segment END), dinv, col
__global__ __launch_bounds__(256) void k_bfinal(const int* __restrict__ pk,
                                                const int* __restrict__ S,
                                                int* cnt, int* rp, float* dinv,
                                                int* col, int e, int n) {
    __shared__ int cl[256];
    __shared__ int sc[256];
    const int b = blockIdx.x;
    const int base = S[b * NB];
    const int end = (b < 255) ? S[(b + 1) * NB] : e;
    cl[threadIdx.x] = 0;
    __syncthreads();
    for (int j = base + threadIdx.x; j < end; j += 256)
        atomicAdd(&cl[(pk[j] >> 16) & 255], 1);
    __syncthreads();
    sc[threadIdx.x] = cl[threadIdx.x];
    __syncthreads();
    for (int off = 1; off < 256; off <<= 1) {
        int t = (threadIdx.x >= off) ? sc[threadIdx.x - off] : 0;
        __syncthreads();
        sc[threadIdx.x] += t;
        __syncthreads();
    }
    const int c = cl[threadIdx.x];
    const int incl = sc[threadIdx.x];
    const int d = b * 256 + threadIdx.x;
    if (d < n) {
        cnt[d] = c;
        rp[d] = base + incl;
        dinv[d] = rsqrtf((float)c + 1.0f);
    }
    __syncthreads();
    sc[threadIdx.x] = base + incl - c;
    __syncthreads();
    for (int j = base + threadIdx.x; j < end; j += 256) {
        int p = pk[j];
        int pos = atomicAdd(&sc[(p >> 16) & 255], 1);
        col[pos] = p & 0xFFFF;
    }
}

// ---------- W fp32[k][j] -> bf16 transposed Wt[j][k] (once per call) ----------
__global__ void k_wcvt(const float* __restrict__ W, unsigned short* __restrict__ Wt) {
    int idx = blockIdx.x * 256 + threadIdx.x;   // 16384 threads
    int k = idx >> 7, j = idx & 127;
    Wt[j * FD + k] = f2bf(W[idx]);
}

// ---------- MFMA GEMM: C[n,128] = act(A[n,128] @ W (+ b)), bf16 out ----------
// Wt (bf16, transposed) staged into LDS (plain 16B copies). Block = 512 thr
// = 8 waves; wave computes 16 rows x 128 cols via 8 N-tiles x 4 K-steps of
// mfma_f32_16x16x32_bf16. A bf16, or fp32 converted in-register (AFP32).
// AV epilogue (Wg): asrc/adst row-dots from fp32 accumulators.
template <bool BIAS_RELU, bool AV, bool AFP32>
__global__ __launch_bounds__(512) void k_gemm_mfma(const void* __restrict__ Av,
                                                   const unsigned short* __restrict__ Wtg,
                                                   const float* __restrict__ b,
                                                   unsigned short* __restrict__ C,
                                                   const float* __restrict__ av_s,
                                                   const float* __restrict__ av_d,
                                                   float* asrc, float* adst, int n) {
    __shared__ unsigned short Wt[FD][136];
    #pragma unroll
    for (int it = 0; it < 4; ++it) {
        int idx = (it * 512 + threadIdx.x) * 8;
        int j = idx >> 7, k = idx & 127;
        *(u16x8*)&Wt[j][k] = *(const u16x8*)&Wtg[idx];
    }
    __syncthreads();

    const int wid = threadIdx.x >> 6;
    const int lane = threadIdx.x & 63;
    const int lm = lane & 15;
    const int lh = lane >> 4;
    const int row0 = blockIdx.x * 128 + wid * 16;

    const int arow = min(row0 + lm, n - 1);
    bf16x8 a0, a1, a2, a3;
    if (AFP32) {
        const float* Ar = (const float*)Av + (size_t)arow * FD + lh * 8;
        #pragma unroll
        for (int kk = 0; kk < 4; ++kk) {
            float4 lo = *(const float4*)(Ar + kk * 32);
            float4 hi = *(const float4*)(Ar + kk * 32 + 4);
            bf16x8 a;
            a[0] = (short)f2bf(lo.x); a[1] = (short)f2bf(lo.y);
            a[2] = (short)f2bf(lo.z); a[3] = (short)f2bf(lo.w);
            a[4] = (short)f2bf(hi.x); a[5] = (short)f2bf(hi.y);
            a[6] = (short)f2bf(hi.z); a[7] = (short)f2bf(hi.w);
            if (kk == 0) a0 = a; else if (kk == 1) a1 = a; else if (kk == 2) a2 = a; else a3 = a;
        }
    } else {
        const unsigned short* Ar = (const unsigned short*)Av + (size_t)arow * FD + lh * 8;
        a0 = *(const bf16x8*)(Ar);
        a1 = *(const bf16x8*)(Ar + 32);
        a2 = *(const bf16x8*)(Ar + 64);
        a3 = *(const bf16x8*)(Ar + 96);
    }

    f32x4 acc[8];
    #pragma unroll
    for (int nt = 0; nt < 8; ++nt) acc[nt] = (f32x4){0.f, 0.f, 0.f, 0.f};

    #pragma unroll
    for (int nt = 0; nt < 8; ++nt) {
        const unsigned short* wp = &Wt[nt * 16 + lm][lh * 8];
        bf16x8 b0 = *(const bf16x8*)(wp);
        bf16x8 b1 = *(const bf16x8*)(wp + 32);
        bf16x8 b2 = *(const bf16x8*)(wp + 64);
        bf16x8 b3 = *(const bf16x8*)(wp + 96);
        acc[nt] = __builtin_amdgcn_mfma_f32_16x16x32_bf16(a0, b0, acc[nt], 0, 0, 0);
        acc[nt] = __builtin_amdgcn_mfma_f32_16x16x32_bf16(a1, b1, acc[nt], 0, 0, 0);
        acc[nt] = __builtin_amdgcn_mfma_f32_16x16x32_bf16(a2, b2, acc[nt], 0, 0, 0);
        acc[nt] = __builtin_amdgcn_mfma_f32_16x16x32_bf16(a3, b3, acc[nt], 0, 0, 0);
    }

    #pragma unroll
    for (int nt = 0; nt < 8; ++nt) {
        const int c = nt * 16 + lm;
        float bv = 0.f;
        if (BIAS_RELU) bv = b[c];
        #pragma unroll
        for (int r = 0; r < 4; ++r) {
            const int row = row0 + 4 * lh + r;
            float v = acc[nt][r];
            if (BIAS_RELU) v = fmaxf(v + bv, 0.f);
            if (row < n) C[(size_t)row * FD + c] = f2bf(v);
        }
    }

    if (AV) {
        float asv[8], adv[8];
        #pragma unroll
        for (int nt = 0; nt < 8; ++nt) {
            asv[nt] = av_s[nt * 16 + lm];
            adv[nt] = av_d[nt * 16 + lm];
        }
        #pragma unroll
        for (int r = 0; r < 4; ++r) {
            float ps = 0.f, pd = 0.f;
            #pragma unroll
            for (int nt = 0; nt < 8; ++nt) {
                ps = fmaf(acc[nt][r], asv[nt], ps);
                pd = fmaf(acc[nt][r], adv[nt], pd);
            }
            #pragma unroll
            for (int m = 1; m < 16; m <<= 1) {
                ps += __shfl_xor(ps, m);
                pd += __shfl_xor(pd, m);
            }
            const int row = row0 + 4 * lh + r;
            if (lm == 0 && row < n) { asrc[row] = ps; adst[row] = pd; }
        }
    }
}

// ---------- fused gather over bf16 rows, bf16 out ----------
// one wave per node; 16 lanes/edge (8 cols each, one ushort8 load), 4 quarters
// take alternate edges, x4 unroll -> 16 edges in flight per wave.
// rp[] holds segment END; beg = rp[d] - cnt[d].
// MODE 0 (GCN): out[d] = relu( sum dinv[s]*dinv[d]*m[s] + bias )
// MODE 1 (GAT): out[d] = ( sum w_sd g[s] ) / ( sum w_sd ), w = exp(lrelu(asrc[s]+adst[d]))
template <int MODE>
__global__ __launch_bounds__(256) void k_gather(const unsigned short* __restrict__ m,
                                                const int* __restrict__ col,
                                                const int* __restrict__ rp,
                                                const int* __restrict__ cnt,
                                                const float* __restrict__ dinv,
                                                const float* __restrict__ bias,
                                                const float* __restrict__ asrc,
                                                const float* __restrict__ adst,
                                                unsigned short* __restrict__ out, int n) {
    const int wave = threadIdx.x >> 6;
    const int lane = threadIdx.x & 63;
    const int q = lane >> 4;      // quarter 0..3
    const int l16 = lane & 15;
    const int d = blockIdx.x * 4 + wave;
    if (d >= n) return;
    const int c0 = l16 * 8;

    const float sd = (MODE == 0) ? dinv[d] : adst[d];

    float acc[8];
    #pragma unroll
    for (int i = 0; i < 8; ++i) acc[i] = 0.f;
    float denom = 0.f;

    if (q == 0) {  // self term
        float w = (MODE == 0) ? sd * sd : expf(lrelu(asrc[d] + sd));
        u16x8 u = *(const u16x8*)(m + (size_t)d * FD + c0);
        #pragma unroll
        for (int i = 0; i < 8; ++i) acc[i] = w * bf2f(u[i]);
        denom = w;
    }

    const int deg = cnt[d];
    const int beg = rp[d] - deg;
    int j = q;

    for (; j + 12 < deg; j += 16) {
        const int s0 = col[beg + j];
        const int s1 = col[beg + j + 4];
        const int s2 = col[beg + j + 8];
        const int s3 = col[beg + j + 12];
        const u16x8 u0 = *(const u16x8*)(m + (size_t)s0 * FD + c0);
        const u16x8 u1 = *(const u16x8*)(m + (size_t)s1 * FD + c0);
        const u16x8 u2 = *(const u16x8*)(m + (size_t)s2 * FD + c0);
        const u16x8 u3 = *(const u16x8*)(m + (size_t)s3 * FD + c0);
        float w0, w1, w2, w3;
        if (MODE == 0) {
            w0 = sd * dinv[s0]; w1 = sd * dinv[s1];
            w2 = sd * dinv[s2]; w3 = sd * dinv[s3];
        } else {
            w0 = expf(lrelu(asrc[s0] + sd)); w1 = expf(lrelu(asrc[s1] + sd));
            w2 = expf(lrelu(asrc[s2] + sd)); w3 = expf(lrelu(asrc[s3] + sd));
        }
        #pragma unroll
        for (int i = 0; i < 8; ++i) {
            acc[i] = fmaf(w0, bf2f(u0[i]), acc[i]);
            acc[i] = fmaf(w1, bf2f(u1[i]), acc[i]);
            acc[i] = fmaf(w2, bf2f(u2[i]), acc[i]);
            acc[i] = fmaf(w3, bf2f(u3[i]), acc[i]);
        }
        if (MODE == 1) denom += w0 + w1 + w2 + w3;
    }
    for (; j < deg; j += 4) {
        const int s = col[beg + j];
        const u16x8 u = *(const u16x8*)(m + (size_t)s * FD + c0);
        float w;
        if (MODE == 0) w = sd * dinv[s];
        else           w = expf(lrelu(asrc[s] + sd));
        #pragma unroll
        for (int i = 0; i < 8; ++i) acc[i] = fmaf(w, bf2f(u[i]), acc[i]);
        if (MODE == 1) denom += w;
    }

    // merge quarters (lanes l16, l16+16, l16+32, l16+48)
    #pragma unroll
    for (int i = 0; i < 8; ++i) {
        acc[i] += __shfl_xor(acc[i], 16);
        acc[i] += __shfl_xor(acc[i], 32);
    }
    if (MODE == 1) {
        denom += __shfl_xor(denom, 16);
        denom += __shfl_xor(denom, 32);
    }

    if (q == 0) {
        float o[8];
        if (MODE == 0) {
            #pragma unroll
            for (int i = 0; i < 8; ++i) o[i] = fmaxf(acc[i] + bias[c0 + i], 0.f);
        } else {
            float inv = 1.0f / denom;
            #pragma unroll
            for (int i = 0; i < 8; ++i) o[i] = acc[i] * inv;
        }
        u16x8 ou;
        #pragma unroll
        for (int i = 0; i < 8; ++i) ou[i] = f2bf(o[i]);
        *(u16x8*)(out + (size_t)d * FD + c0) = ou;
    }
}

// ---------- final mean over nodes ----------
__global__ void k_zero_out(float* out) { out[threadIdx.x] = 0.f; }

__global__ void k_reduce_plain(const unsigned short* __restrict__ val, float* out, int n) {
    const int sub = threadIdx.x >> 7;
    const int c = threadIdx.x & 127;
    float r = 0.f;
    for (int i = blockIdx.x * 2 + sub; i < n; i += gridDim.x * 2)
        r += bf2f(val[(size_t)i * FD + c]);
    __shared__ float lds[256];
    lds[threadIdx.x] = r;
    __syncthreads();
    if (threadIdx.x < 128) atomicAdd(&out[c], lds[threadIdx.x] + lds[threadIdx.x + 128]);
}

__global__ void k_final(float* out, const float* __restrict__ bg, float invn) {
    int c = threadIdx.x;
    out[c] = out[c] * invn + bg[c];
}

// ---------- launch ----------
extern "C" void kernel_launch(void* const* d_in, const int* in_sizes, int n_in,
                              void* d_out, int out_size, void* d_ws, size_t ws_size,
                              hipStream_t stream) {
    const float* x      = (const float*)d_in[0];
    const int*   ei     = (const int*)d_in[1];
    const float* W_emb  = (const float*)d_in[2];
    const float* b_emb  = (const float*)d_in[3];
    const float* W1     = (const float*)d_in[4];
    const float* b1     = (const float*)d_in[5];
    const float* W2     = (const float*)d_in[6];
    const float* b2     = (const float*)d_in[7];
    const float* Wg     = (const float*)d_in[8];
    const float* a_src  = (const float*)d_in[9];
    const float* a_dst  = (const float*)d_in[10];
    const float* bg     = (const float*)d_in[11];

    const int n = in_sizes[0] / FD;   // 50000
    const int e = in_sizes[1] / 2;    // 800000
    const int* src = ei;
    const int* dst = ei + e;

    unsigned short* bufA = (unsigned short*)d_ws;           // n*128 bf16
    unsigned short* bufB = bufA + (size_t)n * FD;           // n*128 bf16
    unsigned short* Wt4  = bufB + (size_t)n * FD;           // 4 * 128*128 bf16
    float* dinv  = (float*)(Wt4 + 4 * FD * FD);
    float* asrc  = dinv + n;
    float* adst  = asrc + n;
    int*   cnt   = (int*)(adst + n);
    int*   rp    = cnt + n;
    int*   col   = rp + n;
    int*   pk    = col + e;
    int*   ghist = pk + e;            // 65536
    int*   Sg    = ghist + NB * 256;  // 65536
    int*   bsum  = Sg + NB * 256;     // 256

    const dim3 B(256);
    const int chunk  = (e + NB - 1) / NB;
    const int gnode4 = (n + 3) / 4;
    const int gb128  = (n + 127) / 128;

    // ---- weights -> bf16 transposed (once) ----
    k_wcvt<<<64, B, 0, stream>>>(W_emb, Wt4 + 0 * FD * FD);
    k_wcvt<<<64, B, 0, stream>>>(W1,    Wt4 + 1 * FD * FD);
    k_wcvt<<<64, B, 0, stream>>>(W2,    Wt4 + 2 * FD * FD);
    k_wcvt<<<64, B, 0, stream>>>(Wg,    Wt4 + 3 * FD * FD);

    // ---- CSR build: MSD bucket sort (LDS atomics only) ----
    k_bhist<<<NB, B, 0, stream>>>(dst, ghist, e, chunk);
    k_scan1<<<256, B, 0, stream>>>(ghist, Sg, bsum, NB * 256);
    k_scan2<<<1, B, 0, stream>>>(bsum, 256);
    k_scan3<<<256, B, 0, stream>>>(Sg, ghist, bsum, NB * 256);
    k_bscatter<<<NB, B, 0, stream>>>(dst, src, Sg, pk, e, chunk);
    k_bfinal<<<256, B, 0, stream>>>(pk, Sg, cnt, rp, dinv, col, e, n);

    // ---- h0 = relu(x @ W_emb + b_emb) -> bufB ----
    k_gemm_mfma<true, false, true><<<gb128, 512, 0, stream>>>(x, Wt4 + 0 * FD * FD, b_emb, bufB,
                                                              nullptr, nullptr, nullptr, nullptr, n);
    // ---- GCN layer 1 ----
    k_gemm_mfma<false, false, false><<<gb128, 512, 0, stream>>>(bufB, Wt4 + 1 * FD * FD, nullptr, bufA,
                                                                nullptr, nullptr, nullptr, nullptr, n);
    k_gather<0><<<gnode4, B, 0, stream>>>(bufA, col, rp, cnt, dinv, b1,
                                          nullptr, nullptr, bufB, n);
    // ---- GCN layer 2 ----
    k_gemm_mfma<false, false, false><<<gb128, 512, 0, stream>>>(bufB, Wt4 + 2 * FD * FD, nullptr, bufA,
                                                                nullptr, nullptr, nullptr, nullptr, n);
    k_gather<0><<<gnode4, B, 0, stream>>>(bufA, col, rp, cnt, dinv, b2,
                                          nullptr, nullptr, bufB, n);
    // ---- GAT ----
    k_gemm_mfma<false, true, false><<<gb128, 512, 0, stream>>>(bufB, Wt4 + 3 * FD * FD, nullptr, bufA,
                                                               a_src, a_dst, asrc, adst, n);
    k_gather<1><<<gnode4, B, 0, stream>>>(bufA, col, rp, cnt, nullptr, nullptr,
                                          asrc, adst, bufB, n);

    // ---- out[c] = mean_i val[i][c] + bg[c] ----
    k_zero_out<<<1, FD, 0, stream>>>((float*)d_out);
    k_reduce_plain<<<256, B, 0, stream>>>(bufB, (float*)d_out, n);
    k_final<<<1, FD, 0, stream>>>((float*)d_out, bg, 1.0f / n);
}

// Round 11
// 224.565 us; speedup vs baseline: 2.1492x; 1.0225x over previous
//
#include <hip/hip_runtime.h>

#define FD 128  // feature dim (H = O = 128)
#define NB 256  // sort buckets / hist blocks

typedef __attribute__((ext_vector_type(8))) short bf16x8;
typedef __attribute__((ext_vector_type(8))) unsigned short u16x8;
typedef __attribute__((ext_vector_type(4))) float f32x4;

__device__ __forceinline__ float lrelu(float x) { return x > 0.f ? x : 0.2f * x; }

__device__ __forceinline__ unsigned short f2bf(float f) {
    unsigned int u = __float_as_uint(f);
    u = (u + 0x7FFFu + ((u >> 16) & 1u)) >> 16;
    return (unsigned short)u;
}
__device__ __forceinline__ float bf2f(unsigned short h) {
    return __uint_as_float((unsigned int)h << 16);
}

// ---------- MFMA GEMM body (shared): C[n,128] = act(A @ W (+ b)), bf16 out ----------
// wave = 16 rows x 128 cols, 8 N-tiles x 4 K-steps of mfma_f32_16x16x32_bf16.
// WF32: stage W from fp32 row-major (convert+transpose); else copy bf16-transposed Wt.
// AFP32: A fp32 (convert in-register); else bf16.
// AV: also emit asrc/adst row-dots (GAT attention scalars) from fp32 accumulators.
template <bool BIAS_RELU, bool AV, bool AFP32, bool WF32>
__device__ __forceinline__ void gemm_body(const void* __restrict__ Av,
                                          const void* __restrict__ Wsrc,
                                          const float* __restrict__ b,
                                          unsigned short* __restrict__ C,
                                          const float* __restrict__ av_s,
                                          const float* __restrict__ av_d,
                                          float* asrc, float* adst, int n, int bid) {
    __shared__ unsigned short Wt[FD][136];
    if (WF32) {
        const float* W = (const float*)Wsrc;
        for (int idx = threadIdx.x; idx < FD * FD; idx += 512) {
            int k = idx >> 7, j = idx & 127;
            Wt[j][k] = f2bf(W[idx]);
        }
    } else {
        const unsigned short* Wtg = (const unsigned short*)Wsrc;
        #pragma unroll
        for (int it = 0; it < 4; ++it) {
            int idx = (it * 512 + threadIdx.x) * 8;
            int j = idx >> 7, k = idx & 127;
            *(u16x8*)&Wt[j][k] = *(const u16x8*)&Wtg[idx];
        }
    }
    __syncthreads();

    const int wid = threadIdx.x >> 6;
    const int lane = threadIdx.x & 63;
    const int lm = lane & 15;
    const int lh = lane >> 4;
    const int row0 = bid * 128 + wid * 16;

    const int arow = min(row0 + lm, n - 1);
    bf16x8 a0, a1, a2, a3;
    if (AFP32) {
        const float* Ar = (const float*)Av + (size_t)arow * FD + lh * 8;
        #pragma unroll
        for (int kk = 0; kk < 4; ++kk) {
            float4 lo = *(const float4*)(Ar + kk * 32);
            float4 hi = *(const float4*)(Ar + kk * 32 + 4);
            bf16x8 a;
            a[0] = (short)f2bf(lo.x); a[1] = (short)f2bf(lo.y);
            a[2] = (short)f2bf(lo.z); a[3] = (short)f2bf(lo.w);
            a[4] = (short)f2bf(hi.x); a[5] = (short)f2bf(hi.y);
            a[6] = (short)f2bf(hi.z); a[7] = (short)f2bf(hi.w);
            if (kk == 0) a0 = a; else if (kk == 1) a1 = a; else if (kk == 2) a2 = a; else a3 = a;
        }
    } else {
        const unsigned short* Ar = (const unsigned short*)Av + (size_t)arow * FD + lh * 8;
        a0 = *(const bf16x8*)(Ar);
        a1 = *(const bf16x8*)(Ar + 32);
        a2 = *(const bf16x8*)(Ar + 64);
        a3 = *(const bf16x8*)(Ar + 96);
    }

    f32x4 acc[8];
    #pragma unroll
    for (int nt = 0; nt < 8; ++nt) acc[nt] = (f32x4){0.f, 0.f, 0.f, 0.f};

    #pragma unroll
    for (int nt = 0; nt < 8; ++nt) {
        const unsigned short* wp = &Wt[nt * 16 + lm][lh * 8];
        bf16x8 b0 = *(const bf16x8*)(wp);
        bf16x8 b1 = *(const bf16x8*)(wp + 32);
        bf16x8 b2 = *(const bf16x8*)(wp + 64);
        bf16x8 b3 = *(const bf16x8*)(wp + 96);
        acc[nt] = __builtin_amdgcn_mfma_f32_16x16x32_bf16(a0, b0, acc[nt], 0, 0, 0);
        acc[nt] = __builtin_amdgcn_mfma_f32_16x16x32_bf16(a1, b1, acc[nt], 0, 0, 0);
        acc[nt] = __builtin_amdgcn_mfma_f32_16x16x32_bf16(a2, b2, acc[nt], 0, 0, 0);
        acc[nt] = __builtin_amdgcn_mfma_f32_16x16x32_bf16(a3, b3, acc[nt], 0, 0, 0);
    }

    #pragma unroll
    for (int nt = 0; nt < 8; ++nt) {
        const int c = nt * 16 + lm;
        float bv = 0.f;
        if (BIAS_RELU) bv = b[c];
        #pragma unroll
        for (int r = 0; r < 4; ++r) {
            const int row = row0 + 4 * lh + r;
            float v = acc[nt][r];
            if (BIAS_RELU) v = fmaxf(v + bv, 0.f);
            if (row < n) C[(size_t)row * FD + c] = f2bf(v);
        }
    }

    if (AV) {
        float asv[8], adv[8];
        #pragma unroll
        for (int nt = 0; nt < 8; ++nt) {
            asv[nt] = av_s[nt * 16 + lm];
            adv[nt] = av_d[nt * 16 + lm];
        }
        #pragma unroll
        for (int r = 0; r < 4; ++r) {
            float ps = 0.f, pd = 0.f;
            #pragma unroll
            for (int nt = 0; nt < 8; ++nt) {
                ps = fmaf(acc[nt][r], asv[nt], ps);
                pd = fmaf(acc[nt][r], adv[nt], pd);
            }
            #pragma unroll
            for (int m = 1; m < 16; m <<= 1) {
                ps += __shfl_xor(ps, m);
                pd += __shfl_xor(pd, m);
            }
            const int row = row0 + 4 * lh + r;
            if (lm == 0 && row < n) { asrc[row] = ps; adst[row] = pd; }
        }
    }
}

// ---------- mega kernel 0: emb-GEMM | bucket-hist | W cvt | zero ----------
// blocks [0, gb)            : h0 = relu(x @ W_emb + b_emb)  (fp32 in, bf16 out)
// blocks [gb, gb+256)       : per-chunk 256-bin histogram of dst>>8
// blocks [gb+256, gb+256+96): W1/W2/Wg fp32 -> bf16 transposed Wt4
// block  gb+352             : zero d_out (128 floats) + counter
__global__ __launch_bounds__(512) void k_mega0(const float* __restrict__ x,
                                               const float* __restrict__ W_emb,
                                               const float* __restrict__ b_emb,
                                               unsigned short* __restrict__ h0,
                                               const int* __restrict__ dst, int* ghist,
                                               int e, int chunk,
                                               const float* __restrict__ W1,
                                               const float* __restrict__ W2,
                                               const float* __restrict__ Wg,
                                               unsigned short* __restrict__ Wt4,
                                               float* out, int* counter, int n, int gb) {
    const int bx = blockIdx.x;
    if (bx < gb) {
        gemm_body<true, false, true, true>(x, W_emb, b_emb, h0,
                                           nullptr, nullptr, nullptr, nullptr, n, bx);
        return;
    }
    if (bx < gb + 256) {
        __shared__ int h[256];
        if (threadIdx.x < 256) h[threadIdx.x] = 0;
        __syncthreads();
        const int blk = bx - gb;
        const int i0 = blk * chunk;
        const int i1 = min(i0 + chunk, e);
        for (int i = i0 + threadIdx.x; i < i1; i += 512)
            atomicAdd(&h[dst[i] >> 8], 1);
        __syncthreads();
        if (threadIdx.x < 256) ghist[threadIdx.x * NB + blk] = h[threadIdx.x];
        return;
    }
    if (bx < gb + 256 + 96) {
        const int elem = (bx - gb - 256) * 512 + threadIdx.x;   // [0, 49152)
        const int sel = elem >> 14;
        const int within = elem & 16383;
        const int k = within >> 7, j = within & 127;
        const float* Ws = (sel == 0) ? W1 : (sel == 1) ? W2 : Wg;
        Wt4[sel * FD * FD + j * FD + k] = f2bf(Ws[within]);
        return;
    }
    // zero block
    if (threadIdx.x < 128) out[threadIdx.x] = 0.f;
    if (threadIdx.x == 128) *counter = 0;
}

// ---------- standalone GEMM ----------
template <bool AV>
__global__ __launch_bounds__(512) void k_gemm(const unsigned short* __restrict__ A,
                                              const unsigned short* __restrict__ Wtg,
                                              unsigned short* __restrict__ C,
                                              const float* __restrict__ av_s,
                                              const float* __restrict__ av_d,
                                              float* asrc, float* adst, int n) {
    gemm_body<false, AV, false, false>(A, Wtg, nullptr, C, av_s, av_d, asrc, adst, n, blockIdx.x);
}

// ---------- scans ----------
__global__ __launch_bounds__(256) void k_scan1(const int* __restrict__ v, int* S, int* bsum, int n) {
    __shared__ int lds[256];
    int i = blockIdx.x * 256 + threadIdx.x;
    int x = (i < n) ? v[i] : 0;
    lds[threadIdx.x] = x;
    __syncthreads();
    for (int off = 1; off < 256; off <<= 1) {
        int t = (threadIdx.x >= off) ? lds[threadIdx.x - off] : 0;
        __syncthreads();
        lds[threadIdx.x] += t;
        __syncthreads();
    }
    if (i < n) S[i] = lds[threadIdx.x];   // inclusive within block
    if (threadIdx.x == 255) bsum[blockIdx.x] = lds[255];
}

__global__ __launch_bounds__(256) void k_scan2(int* bsum, int nb) {
    __shared__ int lds[256];
    int v = (threadIdx.x < nb) ? bsum[threadIdx.x] : 0;
    lds[threadIdx.x] = v;
    __syncthreads();
    for (int off = 1; off < 256; off <<= 1) {
        int t = (threadIdx.x >= off) ? lds[threadIdx.x - off] : 0;
        __syncthreads();
        lds[threadIdx.x] += t;
        __syncthreads();
    }
    if (threadIdx.x < nb) bsum[threadIdx.x] = lds[threadIdx.x];   // inclusive
}

// exclusive offset on the fly: idx = bin*NB + blk, scan1-block = bin
// S_excl[idx] = S_incl[idx] - v[idx] + (bin>0 ? bsum[bin-1] : 0)

// ---------- bucket scatter: (d<<16)|s into bucket-contiguous pk ----------
__global__ __launch_bounds__(256) void k_bscatter(const int* __restrict__ dst,
                                                  const int* __restrict__ src,
                                                  const int* __restrict__ S,
                                                  const int* __restrict__ gh,
                                                  const int* __restrict__ bsum,
                                                  int* pk, int e, int chunk) {
    __shared__ int cur[256];
    const int t = threadIdx.x;
    const int idx = t * NB + blockIdx.x;
    cur[t] = S[idx] - gh[idx] + ((t > 0) ? bsum[t - 1] : 0);
    __syncthreads();
    const int i0 = blockIdx.x * chunk;
    const int i1 = min(i0 + chunk, e);
    for (int i = i0 + t; i < i1; i += 256) {
        int d = dst[i];
        int s = src[i];
        int pos = atomicAdd(&cur[d >> 8], 1);
        pk[pos] = (d << 16) | s;
    }
}

// ---------- per-bucket finalize: cnt, rp (segment END), dinv, col ----------
__global__ __launch_bounds__(256) void k_bfinal(const int* __restrict__ pk,
                                                const int* __restrict__ S,
                                                const int* __restrict__ gh,
                                                const int* __restrict__ bsum,
                                                int* cnt, int* rp, float* dinv,
                                                int* col, int e, int n) {
    __shared__ int cl[256];
    __shared__ int sc[256];
    const int b = blockIdx.x;
    const int i0 = b * NB;
    const int base = S[i0] - gh[i0] + ((b > 0) ? bsum[b - 1] : 0);
    int end;
    if (b < 255) {
        const int i1 = (b + 1) * NB;
        end = S[i1] - gh[i1] + bsum[b];
    } else {
        end = e;
    }
    cl[threadIdx.x] = 0;
    __syncthreads();
    for (int j = base + threadIdx.x; j < end; j += 256)
        atomicAdd(&cl[(pk[j] >> 16) & 255], 1);
    __syncthreads();
    sc[threadIdx.x] = cl[threadIdx.x];
    __syncthreads();
    for (int off = 1; off < 256; off <<= 1) {
        int t = (threadIdx.x >= off) ? sc[threadIdx.x - off] : 0;
        __syncthreads();
        sc[threadIdx.x] += t;
        __syncthreads();
    }
    const int c = cl[threadIdx.x];
    const int incl = sc[threadIdx.x];
    const int d = b * 256 + threadIdx.x;
    if (d < n) {
        cnt[d] = c;
        rp[d] = base + incl;
        dinv[d] = rsqrtf((float)c + 1.0f);
    }
    __syncthreads();
    sc[threadIdx.x] = base + incl - c;
    __syncthreads();
    for (int j = base + threadIdx.x; j < end; j += 256) {
        int p = pk[j];
        int pos = atomicAdd(&sc[(p >> 16) & 255], 1);
        col[pos] = p & 0xFFFF;
    }
}

// ---------- fused gather over bf16 rows, bf16 out ----------
// one wave per node; 16 lanes/edge (8 cols each), 4 quarters alternate edges,
// x4 unroll -> 16 edges in flight (matches mean degree ~16).
template <int MODE>
__global__ __launch_bounds__(256) void k_gather(const unsigned short* __restrict__ m,
                                                const int* __restrict__ col,
                                                const int* __restrict__ rp,
                                                const int* __restrict__ cnt,
                                                const float* __restrict__ dinv,
                                                const float* __restrict__ bias,
                                                const float* __restrict__ asrc,
                                                const float* __restrict__ adst,
                                                unsigned short* __restrict__ out, int n) {
    const int wave = threadIdx.x >> 6;
    const int lane = threadIdx.x & 63;
    const int q = lane >> 4;
    const int l16 = lane & 15;
    const int d = blockIdx.x * 4 + wave;
    if (d >= n) return;
    const int c0 = l16 * 8;

    const float sd = (MODE == 0) ? dinv[d] : adst[d];

    float acc[8];
    #pragma unroll
    for (int i = 0; i < 8; ++i) acc[i] = 0.f;
    float denom = 0.f;

    if (q == 0) {  // self term
        float w = (MODE == 0) ? sd * sd : expf(lrelu(asrc[d] + sd));
        u16x8 u = *(const u16x8*)(m + (size_t)d * FD + c0);
        #pragma unroll
        for (int i = 0; i < 8; ++i) acc[i] = w * bf2f(u[i]);
        denom = w;
    }

    const int deg = cnt[d];
    const int beg = rp[d] - deg;
    int j = q;

    for (; j + 12 < deg; j += 16) {
        const int s0 = col[beg + j];
        const int s1 = col[beg + j + 4];
        const int s2 = col[beg + j + 8];
        const int s3 = col[beg + j + 12];
        const u16x8 u0 = *(const u16x8*)(m + (size_t)s0 * FD + c0);
        const u16x8 u1 = *(const u16x8*)(m + (size_t)s1 * FD + c0);
        const u16x8 u2 = *(const u16x8*)(m + (size_t)s2 * FD + c0);
        const u16x8 u3 = *(const u16x8*)(m + (size_t)s3 * FD + c0);
        float w0, w1, w2, w3;
        if (MODE == 0) {
            w0 = sd * dinv[s0]; w1 = sd * dinv[s1];
            w2 = sd * dinv[s2]; w3 = sd * dinv[s3];
        } else {
            w0 = expf(lrelu(asrc[s0] + sd)); w1 = expf(lrelu(asrc[s1] + sd));
            w2 = expf(lrelu(asrc[s2] + sd)); w3 = expf(lrelu(asrc[s3] + sd));
        }
        #pragma unroll
        for (int i = 0; i < 8; ++i) {
            acc[i] = fmaf(w0, bf2f(u0[i]), acc[i]);
            acc[i] = fmaf(w1, bf2f(u1[i]), acc[i]);
            acc[i] = fmaf(w2, bf2f(u2[i]), acc[i]);
            acc[i] = fmaf(w3, bf2f(u3[i]), acc[i]);
        }
        if (MODE == 1) denom += w0 + w1 + w2 + w3;
    }
    for (; j < deg; j += 4) {
        const int s = col[beg + j];
        const u16x8 u = *(const u16x8*)(m + (size_t)s * FD + c0);
        float w;
        if (MODE == 0) w = sd * dinv[s];
        else           w = expf(lrelu(asrc[s] + sd));
        #pragma unroll
        for (int i = 0; i < 8; ++i) acc[i] = fmaf(w, bf2f(u[i]), acc[i]);
        if (MODE == 1) denom += w;
    }

    #pragma unroll
    for (int i = 0; i < 8; ++i) {
        acc[i] += __shfl_xor(acc[i], 16);
        acc[i] += __shfl_xor(acc[i], 32);
    }
    if (MODE == 1) {
        denom += __shfl_xor(denom, 16);
        denom += __shfl_xor(denom, 32);
    }

    if (q == 0) {
        float o[8];
        if (MODE == 0) {
            #pragma unroll
            for (int i = 0; i < 8; ++i) o[i] = fmaxf(acc[i] + bias[c0 + i], 0.f);
        } else {
            float inv = 1.0f / denom;
            #pragma unroll
            for (int i = 0; i < 8; ++i) o[i] = acc[i] * inv;
        }
        u16x8 ou;
        #pragma unroll
        for (int i = 0; i < 8; ++i) ou[i] = f2bf(o[i]);
        *(u16x8*)(out + (size_t)d * FD + c0) = ou;
    }
}

// ---------- mean over nodes + final scale/bias (last-block pattern) ----------
__global__ __launch_bounds__(256) void k_reduce(const unsigned short* __restrict__ val,
                                                float* out, const float* __restrict__ bg,
                                                int* counter, int n, float invn) {
    const int sub = threadIdx.x >> 7;
    const int c = threadIdx.x & 127;
    float r = 0.f;
    for (int i = blockIdx.x * 2 + sub; i < n; i += gridDim.x * 2)
        r += bf2f(val[(size_t)i * FD + c]);
    __shared__ float lds[256];
    lds[threadIdx.x] = r;
    __syncthreads();
    if (threadIdx.x < 128) atomicAdd(&out[c], lds[threadIdx.x] + lds[threadIdx.x + 128]);
    __syncthreads();
    __threadfence();
    __shared__ int lastflag;
    if (threadIdx.x == 0) {
        int old = atomicAdd(counter, 1);
        lastflag = (old == (int)gridDim.x - 1);
    }
    __syncthreads();
    if (lastflag) {
        __threadfence();
        if (threadIdx.x < 128) {
            float v = atomicAdd(&out[threadIdx.x], 0.0f);  // coherent read
            out[threadIdx.x] = v * invn + bg[threadIdx.x];
        }
    }
}

// ---------- launch ----------
extern "C" void kernel_launch(void* const* d_in, const int* in_sizes, int n_in,
                              void* d_out, int out_size, void* d_ws, size_t ws_size,
                              hipStream_t stream) {
    const float* x      = (const float*)d_in[0];
    const int*   ei     = (const int*)d_in[1];
    const float* W_emb  = (const float*)d_in[2];
    const float* b_emb  = (const float*)d_in[3];
    const float* W1     = (const float*)d_in[4];
    const float* b1     = (const float*)d_in[5];
    const float* W2     = (const float*)d_in[6];
    const float* b2     = (const float*)d_in[7];
    const float* Wg     = (const float*)d_in[8];
    const float* a_src  = (const float*)d_in[9];
    const float* a_dst  = (const float*)d_in[10];
    const float* bg     = (const float*)d_in[11];

    const int n = in_sizes[0] / FD;   // 50000
    const int e = in_sizes[1] / 2;    // 800000
    const int* src = ei;
    const int* dst = ei + e;

    unsigned short* bufA = (unsigned short*)d_ws;           // n*128 bf16
    unsigned short* bufB = bufA + (size_t)n * FD;           // n*128 bf16
    unsigned short* Wt4  = bufB + (size_t)n * FD;           // 3 * 128*128 bf16
    float* dinv  = (float*)(Wt4 + 3 * FD * FD);
    float* asrc  = dinv + n;
    float* adst  = asrc + n;
    int*   cnt   = (int*)(adst + n);
    int*   rp    = cnt + n;
    int*   col   = rp + n;
    int*   pk    = col + e;
    int*   ghist = pk + e;            // 65536
    int*   Sg    = ghist + NB * 256;  // 65536
    int*   bsum  = Sg + NB * 256;     // 256
    int*   counter = bsum + 256;      // 1

    const dim3 B(256);
    const int chunk  = (e + NB - 1) / NB;
    const int gnode4 = (n + 3) / 4;
    const int gb128  = (n + 127) / 128;   // 391

    // 1) mega0: emb-GEMM | bhist | wcvt | zero   (all independent)
    k_mega0<<<gb128 + 256 + 96 + 1, 512, 0, stream>>>(x, W_emb, b_emb, bufB,
                                                      dst, ghist, e, chunk,
                                                      W1, W2, Wg, Wt4,
                                                      (float*)d_out, counter, n, gb128);
    // 2-5) sort
    k_scan1<<<256, B, 0, stream>>>(ghist, Sg, bsum, NB * 256);
    k_scan2<<<1, B, 0, stream>>>(bsum, 256);
    k_bscatter<<<NB, B, 0, stream>>>(dst, src, Sg, ghist, bsum, pk, e, chunk);
    k_bfinal<<<256, B, 0, stream>>>(pk, Sg, ghist, bsum, cnt, rp, dinv, col, e, n);

    // 6-7) GCN layer 1
    k_gemm<false><<<gb128, 512, 0, stream>>>(bufB, Wt4 + 0 * FD * FD, bufA,
                                             nullptr, nullptr, nullptr, nullptr, n);
    k_gather<0><<<gnode4, B, 0, stream>>>(bufA, col, rp, cnt, dinv, b1,
                                          nullptr, nullptr, bufB, n);
    // 8-9) GCN layer 2
    k_gemm<false><<<gb128, 512, 0, stream>>>(bufB, Wt4 + 1 * FD * FD, bufA,
                                             nullptr, nullptr, nullptr, nullptr, n);
    k_gather<0><<<gnode4, B, 0, stream>>>(bufA, col, rp, cnt, dinv, b2,
                                          nullptr, nullptr, bufB, n);
    // 10-11) GAT
    k_gemm<true><<<gb128, 512, 0, stream>>>(bufB, Wt4 + 2 * FD * FD, bufA,
                                            a_src, a_dst, asrc, adst, n);
    k_gather<1><<<gnode4, B, 0, stream>>>(bufA, col, rp, cnt, nullptr, nullptr,
                                          asrc, adst, bufB, n);
    // 12) mean + final
    k_reduce<<<256, B, 0, stream>>>(bufB, (float*)d_out, bg, counter, n, 1.0f / n);
}